// Round 10
// baseline (281.472 us; speedup 1.0000x reference)
//
#include <hip/hip_runtime.h>
#include <math.h>

#define NN 100000
#define NE 1600000
#define D 128
#define BN_EPS 1e-5f
#define NCHUNK 391   // ceil(NN/256)
#define GSZ4 25000   // hist group node range (4 groups)
#define GSZ2 50000   // scatter group node range (2 groups)
#define NCH 64       // edge chunks
#define CH 25000     // NE / NCH
#define HW8 6250     // words per hist half (4 nodes/word, 8-bit packed)
#define HSTR 12500   // words per (group,chunk) slice: [0,HW8)=cnt, [HW8,2*HW8)=deg

typedef __attribute__((ext_vector_type(8))) short short8;
typedef __attribute__((ext_vector_type(4))) float f32x4;
typedef __attribute__((ext_vector_type(2))) float f32x2;

// ws layout (bytes):
// dinv   [0,        400000)
// cnt    [400000,   800000)
// off    [800000,  1200000)
// part   [1200000, 1202048)
// sums8  [1202048, 1210240)   8 x 256 floats ([0..127]=s, [128..255]=s2)
// esrc   [1210368, 7610368)   src per CSR slot
// hist   [7610368, 20410368)  12.8 MB (4 groups x 64 chunks x 12500 words)
// xh     [20410368,46010368)  x bf16 packed [NN][64] uints; reused as relu-bf16 rh
// Wht    [46010368,46043136)
// high-water 46.05 MB (round 2 proved >= 52 MB available)

__device__ __forceinline__ unsigned bf_rne(float f) {
    unsigned u = __float_as_uint(f);
    return (u + 0x7fffu + ((u >> 16) & 1u)) >> 16;
}
__device__ __forceinline__ unsigned pk2(float lo, float hi) {
    return bf_rne(lo) | (bf_rne(hi) << 16);
}

// ---- kernel 1: per-(chunk,group) LDS histograms (8-bit packed) + fused x->bf16 -
// 4 groups of 25000 nodes; per-chunk per-node counts << 255 -> no byte carry.
// Each of the 256 blocks also converts a 25000-uint slice of x to xh (independent).
__global__ __launch_bounds__(512) void k_hist(const int* __restrict__ ei,
                                              unsigned* __restrict__ hist,
                                              const float* __restrict__ x,
                                              unsigned* __restrict__ xh) {
    __shared__ unsigned loc[HSTR];  // 50 KB
    const int g = blockIdx.x & 3;
    const int t = blockIdx.x >> 2;
    const int lo = g * GSZ4, hi = lo + GSZ4;
    for (int j = threadIdx.x; j < HSTR; j += 512) loc[j] = 0u;
    __syncthreads();
    const int end = t * CH + CH;
    for (int i = t * CH + threadIdx.x; i < end; i += 512) {
        int r = __builtin_nontemporal_load(ei + i);
        int c = __builtin_nontemporal_load(ei + NE + i);
        if (r != c) {
            if (c >= lo && c < hi) {
                int q = c - lo;
                atomicAdd(&loc[q >> 2], 1u << ((q & 3) << 3));
            }
            if (r >= lo && r < hi) {
                int q = r - lo;
                atomicAdd(&loc[HW8 + (q >> 2)], 1u << ((q & 3) << 3));
            }
        }
    }
    // fused conversion: 256 blocks x 25000 uints = NN*64 exactly
    const int base2 = blockIdx.x * 25000;
    for (int j = threadIdx.x; j < 25000; j += 512) {
        f32x2 v = __builtin_nontemporal_load((const f32x2*)x + base2 + j);
        xh[base2 + j] = pk2(v.x, v.y);
    }
    __syncthreads();
    unsigned* dst = hist + (unsigned)(g * NCH + t) * HSTR;
    for (int j = threadIdx.x; j < HSTR; j += 512) dst[j] = loc[j];
}

// ---- kernel 2: reduce hists -> cnt, dinv; in-place chunk prefixes; + cvtw ------
__global__ __launch_bounds__(256) void k_reduce(unsigned* __restrict__ hist,
                                                unsigned* __restrict__ cnt,
                                                float* __restrict__ dinv,
                                                const float* __restrict__ W,
                                                unsigned short* __restrict__ Wht) {
    int id = blockIdx.x * 256 + threadIdx.x;
    if (id < 4 * HW8) {
        int g = id / HW8;
        int w = id - g * HW8;
        unsigned base = (unsigned)(g * NCH) * HSTR + w;
        unsigned r0 = 0, r1 = 0, r2 = 0, r3 = 0;
        unsigned s0 = 0, s1 = 0, s2 = 0, s3 = 0;
        for (int t = 0; t < NCH; ++t) {
            unsigned idx = base + (unsigned)t * HSTR;
            unsigned v = hist[idx];
            hist[idx] = r0 | (r1 << 8) | (r2 << 16) | (r3 << 24);  // excl prefix
            r0 += v & 255u; r1 += (v >> 8) & 255u;
            r2 += (v >> 16) & 255u; r3 += v >> 24;
            unsigned d = hist[idx + HW8];
            s0 += d & 255u; s1 += (d >> 8) & 255u;
            s2 += (d >> 16) & 255u; s3 += d >> 24;
        }
        int n0 = g * GSZ4 + 4 * w;
        cnt[n0]     = r0; cnt[n0 + 1] = r1; cnt[n0 + 2] = r2; cnt[n0 + 3] = r3;
        dinv[n0]     = rsqrtf((float)(s0 + 1u));  // +1 self-loop
        dinv[n0 + 1] = rsqrtf((float)(s1 + 1u));
        dinv[n0 + 2] = rsqrtf((float)(s2 + 1u));
        dinv[n0 + 3] = rsqrtf((float)(s3 + 1u));
    } else {
        int i = id - 4 * HW8;  // W[k][c] -> Wht[c][k]
        if (i < D * D) {
            int k = i >> 7, c = i & 127;
            Wht[c * D + k] = (unsigned short)bf_rne(W[i]);
        }
    }
}

// ---------------- scan step 1: per-chunk sums -----------------------------------
__global__ __launch_bounds__(256) void k_scan1(const unsigned* __restrict__ cnt,
                                               unsigned* __restrict__ part) {
    __shared__ unsigned s[256];
    int i = blockIdx.x * 256 + threadIdx.x;
    unsigned v = (i < NN) ? cnt[i] : 0u;
    s[threadIdx.x] = v;
    __syncthreads();
    for (int o = 128; o > 0; o >>= 1) {
        if (threadIdx.x < o) s[threadIdx.x] += s[threadIdx.x + o];
        __syncthreads();
    }
    if (threadIdx.x == 0) part[blockIdx.x] = s[0];
}

// ------- scan step 2: exclusive scan of partials (1 block); zero sums8 ----------
__global__ __launch_bounds__(512) void k_scan2(unsigned* __restrict__ part,
                                               float* __restrict__ sums8) {
    __shared__ unsigned s[512];
    int t = threadIdx.x;
    for (int j = t; j < 2048; j += 512) sums8[j] = 0.f;
    unsigned v = (t < NCHUNK) ? part[t] : 0u;
    s[t] = v;
    __syncthreads();
    for (int o = 1; o < 512; o <<= 1) {
        unsigned add = (t >= o) ? s[t - o] : 0u;
        __syncthreads();
        s[t] += add;
        __syncthreads();
    }
    if (t < NCHUNK) part[t] = s[t] - v;  // exclusive
}

// ---------------- scan step 3: per-chunk exclusive offsets ----------------------
__global__ __launch_bounds__(256) void k_scan3(const unsigned* __restrict__ cnt,
                                               const unsigned* __restrict__ part,
                                               unsigned* __restrict__ off) {
    __shared__ unsigned s[256];
    int i = blockIdx.x * 256 + threadIdx.x;
    int t = threadIdx.x;
    unsigned v = (i < NN) ? cnt[i] : 0u;
    s[t] = v;
    __syncthreads();
    for (int o = 1; o < 256; o <<= 1) {
        unsigned add = (t >= o) ? s[t - o] : 0u;
        __syncthreads();
        s[t] += add;
        __syncthreads();
    }
    if (i < NN) off[i] = part[blockIdx.x] + s[t] - v;  // exclusive
}

// ---- kernel 3: 2-group scatter via 8-bit packed LDS cursors --------------------
// Group g covers 50000 nodes (cursors 12500 words = 50 KB). Byte cursor =
// chunk prefix (<=60) + in-chunk count (<=~10) << 255: carry-free. Node n0=lo+4j
// maps directly to one hist word (same 4-node packing).
__global__ __launch_bounds__(512) void k_scatter(const int* __restrict__ ei,
                                                 const unsigned* __restrict__ off,
                                                 const unsigned* __restrict__ hist,
                                                 int* __restrict__ esrc) {
    __shared__ unsigned curs[GSZ2 / 4];  // 50 KB
    const int g = blockIdx.x & 1;
    const int t = blockIdx.x >> 1;
    const int lo = g * GSZ2, hi = lo + GSZ2;
    for (int j = threadIdx.x; j < GSZ2 / 4; j += 512) {
        int g4 = 2 * g + (j >= HW8);
        int w4 = (j >= HW8) ? (j - HW8) : j;
        curs[j] = hist[(unsigned)(g4 * NCH + t) * HSTR + w4];
    }
    __syncthreads();
    const int end = t * CH + CH;
    for (int i = t * CH + threadIdx.x; i < end; i += 512) {
        int r = __builtin_nontemporal_load(ei + i);
        int c = __builtin_nontemporal_load(ei + NE + i);
        if (r == c || c < lo || c >= hi) continue;
        int q = c - lo;
        unsigned sh = (q & 3) << 3;
        unsigned old = atomicAdd(&curs[q >> 2], 1u << sh);  // LDS atomic
        unsigned pos = off[c] + ((old >> sh) & 255u);
        esrc[pos] = r;  // L2-local slice, plain store
    }
}

// -------- kernel 4: gather bf16 rows: out_c = dc*(dc*x_c + sum dr*x_r) ----------
__global__ __launch_bounds__(256) void k_gather(const unsigned* __restrict__ xh,
                                                const float* __restrict__ dinv,
                                                const unsigned* __restrict__ off,
                                                const unsigned* __restrict__ cnt,
                                                const int* __restrict__ esrc,
                                                float* __restrict__ out) {
    const int lane = threadIdx.x & 63;
    const int wave = threadIdx.x >> 6;
    const int c = blockIdx.x * 4 + wave;
    if (c >= NN) return;

    const float dc = dinv[c];
    unsigned xc = xh[c * 64 + lane];
    float al = dc * __uint_as_float(xc << 16);
    float ah = dc * __uint_as_float(xc & 0xffff0000u);

    const int base = off[c];
    const int n = cnt[c];
    int i = 0;
    for (; i + 8 <= n; i += 8) {
        int   sv[8];
        float wv[8];
        unsigned pv[8];
        #pragma unroll
        for (int j = 0; j < 8; ++j) sv[j] = esrc[base + i + j];
        #pragma unroll
        for (int j = 0; j < 8; ++j) wv[j] = dinv[sv[j]];
        #pragma unroll
        for (int j = 0; j < 8; ++j) pv[j] = xh[sv[j] * 64 + lane];
        #pragma unroll
        for (int j = 0; j < 8; ++j) {
            al = fmaf(wv[j], __uint_as_float(pv[j] << 16), al);
            ah = fmaf(wv[j], __uint_as_float(pv[j] & 0xffff0000u), ah);
        }
    }
    for (; i + 4 <= n; i += 4) {
        int s0 = esrc[base + i], s1 = esrc[base + i + 1];
        int s2 = esrc[base + i + 2], s3 = esrc[base + i + 3];
        float w0 = dinv[s0], w1 = dinv[s1], w2 = dinv[s2], w3 = dinv[s3];
        unsigned p0 = xh[s0 * 64 + lane], p1 = xh[s1 * 64 + lane];
        unsigned p2 = xh[s2 * 64 + lane], p3 = xh[s3 * 64 + lane];
        al = fmaf(w0, __uint_as_float(p0 << 16), al);
        ah = fmaf(w0, __uint_as_float(p0 & 0xffff0000u), ah);
        al = fmaf(w1, __uint_as_float(p1 << 16), al);
        ah = fmaf(w1, __uint_as_float(p1 & 0xffff0000u), ah);
        al = fmaf(w2, __uint_as_float(p2 << 16), al);
        ah = fmaf(w2, __uint_as_float(p2 & 0xffff0000u), ah);
        al = fmaf(w3, __uint_as_float(p3 << 16), al);
        ah = fmaf(w3, __uint_as_float(p3 & 0xffff0000u), ah);
    }
    for (; i < n; ++i) {
        int s0 = esrc[base + i];
        float w0 = dinv[s0];
        unsigned p0 = xh[s0 * 64 + lane];
        al = fmaf(w0, __uint_as_float(p0 << 16), al);
        ah = fmaf(w0, __uint_as_float(p0 & 0xffff0000u), ah);
    }
    al *= dc;
    ah *= dc;
    *(float2*)&out[c * D + 2 * lane] = make_float2(al, ah);
}

// ---- kernel 5: MFMA GEMM + bias + ReLU -> bf16 rh + fused BN partial stats -----
// Reads agg fp32 from d_out, writes relu bf16 to rh (dead xh region).
__global__ __launch_bounds__(256, 1) void k_gemm(const float* __restrict__ out,
                                                 unsigned short* __restrict__ rh,
                                                 const unsigned short* __restrict__ Wht,
                                                 const float* __restrict__ b,
                                                 float* __restrict__ sums8) {
    __shared__ float sums_lds[256];
    const int lane = threadIdx.x & 63;
    const int wv = threadIdx.x >> 6;
    const int l15 = lane & 15, l4 = lane >> 4;

    if (threadIdx.x < 256) sums_lds[threadIdx.x] = 0.f;
    __syncthreads();

    short8 bfr[8][4];
    #pragma unroll
    for (int n = 0; n < 8; ++n)
        #pragma unroll
        for (int kk = 0; kk < 4; ++kk)
            bfr[n][kk] = *(const short8*)(Wht + (n * 16 + l15) * D + kk * 32 + l4 * 8);

    float bias8[8];
    #pragma unroll
    for (int n = 0; n < 8; ++n) bias8[n] = b[n * 16 + l15];

    float sl[8], s2l[8];
    #pragma unroll
    for (int n = 0; n < 8; ++n) { sl[n] = 0.f; s2l[n] = 0.f; }

    const int gw = blockIdx.x * 4 + wv;
    #pragma unroll
    for (int t = 0; t < 2; ++t) {
        const int tile = gw * 2 + t;
        if (tile < NN / 16) {
            const int row0 = tile * 16;
            short8 af[4];
            #pragma unroll
            for (int kk = 0; kk < 4; ++kk) {
                const float* ar = out + (row0 + l15) * D + kk * 32 + l4 * 8;
                float4 a0 = *(const float4*)ar;
                float4 a1 = *(const float4*)(ar + 4);
                union { short8 s; unsigned u[4]; } cv;
                cv.u[0] = pk2(a0.x, a0.y);
                cv.u[1] = pk2(a0.z, a0.w);
                cv.u[2] = pk2(a1.x, a1.y);
                cv.u[3] = pk2(a1.z, a1.w);
                af[kk] = cv.s;
            }
            f32x4 acc[8];
            #pragma unroll
            for (int n = 0; n < 8; ++n) acc[n] = (f32x4){0.f, 0.f, 0.f, 0.f};
            #pragma unroll
            for (int n = 0; n < 8; ++n)
                #pragma unroll
                for (int kk = 0; kk < 4; ++kk)
                    acc[n] = __builtin_amdgcn_mfma_f32_16x16x32_bf16(af[kk], bfr[n][kk],
                                                                     acc[n], 0, 0, 0);
            #pragma unroll
            for (int n = 0; n < 8; ++n)
                #pragma unroll
                for (int j = 0; j < 4; ++j) {
                    int row = row0 + l4 * 4 + j;
                    float v = fmaxf(acc[n][j] + bias8[n], 0.f);
                    rh[row * D + n * 16 + l15] = (unsigned short)bf_rne(v);
                    sl[n] += v;
                    s2l[n] = fmaf(v, v, s2l[n]);
                }
        }
    }

    // column reduce: lanes sharing l15 across the 4 l4-groups
    #pragma unroll
    for (int n = 0; n < 8; ++n) {
        float a = sl[n], q = s2l[n];
        a += __shfl_xor(a, 16); a += __shfl_xor(a, 32);
        q += __shfl_xor(q, 16); q += __shfl_xor(q, 32);
        if (l4 == 0) {
            atomicAdd(&sums_lds[n * 16 + l15], a);
            atomicAdd(&sums_lds[128 + n * 16 + l15], q);
        }
    }
    __syncthreads();
    if (threadIdx.x < 256)
        unsafeAtomicAdd(&sums8[(blockIdx.x & 7) * 256 + threadIdx.x],
                        sums_lds[threadIdx.x]);
}

// ------------- kernel 6: out = rh_bf16 * scale + shift (BN affine) --------------
__global__ __launch_bounds__(256) void k_apply(const unsigned* __restrict__ rh,
                                               float* __restrict__ out,
                                               const float* __restrict__ gamma,
                                               const float* __restrict__ beta,
                                               const float* __restrict__ sums8) {
    const float invN = 1.f / (float)NN;
    const int tid = blockIdx.x * blockDim.x + threadIdx.x;
    const int stride = gridDim.x * blockDim.x;
    const int c4 = (tid & 31) * 4;

    float4 s4 = make_float4(0.f, 0.f, 0.f, 0.f);
    float4 q4 = make_float4(0.f, 0.f, 0.f, 0.f);
    #pragma unroll
    for (int k = 0; k < 8; ++k) {
        float4 a = *(const float4*)&sums8[k * 256 + c4];
        float4 q = *(const float4*)&sums8[k * 256 + 128 + c4];
        s4.x += a.x; s4.y += a.y; s4.z += a.z; s4.w += a.w;
        q4.x += q.x; q4.y += q.y; q4.z += q.z; q4.w += q.w;
    }
    float4 g4 = *(const float4*)&gamma[c4];
    float4 be = *(const float4*)&beta[c4];

    float mx = s4.x * invN, my = s4.y * invN, mz = s4.z * invN, mw = s4.w * invN;
    float scx = g4.x * rsqrtf(fmaxf(q4.x * invN - mx * mx, 0.f) + BN_EPS);
    float scy = g4.y * rsqrtf(fmaxf(q4.y * invN - my * my, 0.f) + BN_EPS);
    float scz = g4.z * rsqrtf(fmaxf(q4.z * invN - mz * mz, 0.f) + BN_EPS);
    float scw = g4.w * rsqrtf(fmaxf(q4.w * invN - mw * mw, 0.f) + BN_EPS);
    float shx = be.x - mx * scx, shy = be.y - my * scy;
    float shz = be.z - mz * scz, shw = be.w - mw * scw;

    for (int idx = tid; idx < NN * (D / 4); idx += stride) {
        const int row = idx >> 5;
        uint2 p = *(const uint2*)&rh[row * 64 + (tid & 31) * 2];
        float4 a;
        a.x = __uint_as_float(p.x << 16);
        a.y = __uint_as_float(p.x & 0xffff0000u);
        a.z = __uint_as_float(p.y << 16);
        a.w = __uint_as_float(p.y & 0xffff0000u);
        a.x = a.x * scx + shx;
        a.y = a.y * scy + shy;
        a.z = a.z * scz + shz;
        a.w = a.w * scw + shw;
        ((float4*)out)[idx] = a;
    }
}

extern "C" void kernel_launch(void* const* d_in, const int* in_sizes, int n_in,
                              void* d_out, int out_size, void* d_ws, size_t ws_size,
                              hipStream_t stream) {
    const float* x     = (const float*)d_in[0];
    const int*   ei    = (const int*)d_in[1];
    const float* W     = (const float*)d_in[2];
    const float* b     = (const float*)d_in[3];
    const float* gamma = (const float*)d_in[4];
    const float* beta  = (const float*)d_in[5];
    float*       out   = (float*)d_out;

    char* ws = (char*)d_ws;
    float*          dinv  = (float*)ws;
    unsigned*       cnt   = (unsigned*)(ws + 400000);
    unsigned*       off   = (unsigned*)(ws + 800000);
    unsigned*       part  = (unsigned*)(ws + 1200000);
    float*          sums8 = (float*)(ws + 1202048);
    int*            esrc  = (int*)(ws + 1210368);
    unsigned*       hist  = (unsigned*)(ws + 7610368);   // 12.8 MB
    unsigned*       xh    = (unsigned*)(ws + 20410368);  // 25.6 MB; rh after gather
    unsigned short* Wht   = (unsigned short*)(ws + 46010368);

    k_hist<<<NCH * 4, 512, 0, stream>>>(ei, hist, x, xh);
    k_reduce<<<(4 * HW8 + D * D + 255) / 256, 256, 0, stream>>>(hist, cnt, dinv, W, Wht);
    k_scan1<<<NCHUNK, 256, 0, stream>>>(cnt, part);
    k_scan2<<<1, 512, 0, stream>>>(part, sums8);
    k_scan3<<<NCHUNK, 256, 0, stream>>>(cnt, part, off);
    k_scatter<<<NCH * 2, 512, 0, stream>>>(ei, off, hist, esrc);
    k_gather<<<25000, 256, 0, stream>>>(xh, dinv, off, cnt, esrc, out);
    k_gemm<<<782, 256, 0, stream>>>(out, (unsigned short*)xh, Wht, b, sums8);
    k_apply<<<2048, 256, 0, stream>>>(xh, out, gamma, beta, sums8);
}

// Round 11
// 262.002 us; speedup vs baseline: 1.0743x; 1.0743x over previous
//
#include <hip/hip_runtime.h>
#include <math.h>

#define NN 100000
#define NE 1600000
#define D 128
#define BN_EPS 1e-5f
#define NCHUNK 391   // ceil(NN/256)
#define GSZ4 25000   // hist/scatter group node range (4 groups)
#define NCH 64       // edge chunks
#define CH 25000     // NE / NCH
#define HW8 6250     // words per hist half (4 nodes/word, 8-bit packed)
#define HSTR 12500   // words per (group,chunk) slice: [0,HW8)=cnt, [HW8,2*HW8)=deg

typedef __attribute__((ext_vector_type(8))) short short8;
typedef __attribute__((ext_vector_type(4))) float f32x4;
typedef __attribute__((ext_vector_type(2))) float f32x2;

// ws layout (bytes):
// dinv   [0,        400000)
// cnt    [400000,   800000)
// off    [800000,  1200000)
// part   [1200000, 1202048)
// sums8  [1202048, 1210240)   8 x 256 floats ([0..127]=s, [128..255]=s2)
// esrc   [1210368, 7610368)   src per CSR slot
// hist   [7610368, 20410368)  12.8 MB (4 groups x 64 chunks x 12500 words)
// xh     [20410368,46010368)  x bf16 packed [NN][64] uints; reused as relu-bf16 rh
// Wht    [46010368,46043136)

__device__ __forceinline__ unsigned bf_rne(float f) {
    unsigned u = __float_as_uint(f);
    return (u + 0x7fffu + ((u >> 16) & 1u)) >> 16;
}
__device__ __forceinline__ unsigned pk2(float lo, float hi) {
    return bf_rne(lo) | (bf_rne(hi) << 16);
}

// ---- kernel 1: per-(chunk,group) LDS histograms (8-bit packed) + fused x->bf16 -
__global__ __launch_bounds__(512) void k_hist(const int* __restrict__ ei,
                                              unsigned* __restrict__ hist,
                                              const float* __restrict__ x,
                                              unsigned* __restrict__ xh) {
    __shared__ unsigned loc[HSTR];  // 50 KB
    const int g = blockIdx.x & 3;
    const int t = blockIdx.x >> 2;
    const int lo = g * GSZ4, hi = lo + GSZ4;
    for (int j = threadIdx.x; j < HSTR; j += 512) loc[j] = 0u;
    __syncthreads();
    const int end = t * CH + CH;
    for (int i = t * CH + threadIdx.x; i < end; i += 512) {
        int r = __builtin_nontemporal_load(ei + i);
        int c = __builtin_nontemporal_load(ei + NE + i);
        if (r != c) {
            if (c >= lo && c < hi) {
                int q = c - lo;
                atomicAdd(&loc[q >> 2], 1u << ((q & 3) << 3));
            }
            if (r >= lo && r < hi) {
                int q = r - lo;
                atomicAdd(&loc[HW8 + (q >> 2)], 1u << ((q & 3) << 3));
            }
        }
    }
    // fused conversion: 256 blocks x 25000 uints = NN*64 exactly
    const int base2 = blockIdx.x * 25000;
    for (int j = threadIdx.x; j < 25000; j += 512) {
        f32x2 v = __builtin_nontemporal_load((const f32x2*)x + base2 + j);
        xh[base2 + j] = pk2(v.x, v.y);
    }
    __syncthreads();
    unsigned* dst = hist + (unsigned)(g * NCH + t) * HSTR;
    for (int j = threadIdx.x; j < HSTR; j += 512) dst[j] = loc[j];
}

// ---- kernel 2: reduce hists -> cnt, dinv; in-place chunk prefixes; + cvtw ------
__global__ __launch_bounds__(256) void k_reduce(unsigned* __restrict__ hist,
                                                unsigned* __restrict__ cnt,
                                                float* __restrict__ dinv,
                                                const float* __restrict__ W,
                                                unsigned short* __restrict__ Wht) {
    int id = blockIdx.x * 256 + threadIdx.x;
    if (id < 4 * HW8) {
        int g = id / HW8;
        int w = id - g * HW8;
        unsigned base = (unsigned)(g * NCH) * HSTR + w;
        unsigned r0 = 0, r1 = 0, r2 = 0, r3 = 0;
        unsigned s0 = 0, s1 = 0, s2 = 0, s3 = 0;
        for (int t = 0; t < NCH; ++t) {
            unsigned idx = base + (unsigned)t * HSTR;
            unsigned v = hist[idx];
            hist[idx] = r0 | (r1 << 8) | (r2 << 16) | (r3 << 24);  // excl prefix
            r0 += v & 255u; r1 += (v >> 8) & 255u;
            r2 += (v >> 16) & 255u; r3 += v >> 24;
            unsigned d = hist[idx + HW8];
            s0 += d & 255u; s1 += (d >> 8) & 255u;
            s2 += (d >> 16) & 255u; s3 += d >> 24;
        }
        int n0 = g * GSZ4 + 4 * w;
        cnt[n0]     = r0; cnt[n0 + 1] = r1; cnt[n0 + 2] = r2; cnt[n0 + 3] = r3;
        dinv[n0]     = rsqrtf((float)(s0 + 1u));  // +1 self-loop
        dinv[n0 + 1] = rsqrtf((float)(s1 + 1u));
        dinv[n0 + 2] = rsqrtf((float)(s2 + 1u));
        dinv[n0 + 3] = rsqrtf((float)(s3 + 1u));
    } else {
        int i = id - 4 * HW8;  // W[k][c] -> Wht[c][k]
        if (i < D * D) {
            int k = i >> 7, c = i & 127;
            Wht[c * D + k] = (unsigned short)bf_rne(W[i]);
        }
    }
}

// ---------------- scan step 1: per-chunk sums -----------------------------------
__global__ __launch_bounds__(256) void k_scan1(const unsigned* __restrict__ cnt,
                                               unsigned* __restrict__ part) {
    __shared__ unsigned s[256];
    int i = blockIdx.x * 256 + threadIdx.x;
    unsigned v = (i < NN) ? cnt[i] : 0u;
    s[threadIdx.x] = v;
    __syncthreads();
    for (int o = 128; o > 0; o >>= 1) {
        if (threadIdx.x < o) s[threadIdx.x] += s[threadIdx.x + o];
        __syncthreads();
    }
    if (threadIdx.x == 0) part[blockIdx.x] = s[0];
}

// ------- scan step 2: exclusive scan of partials (1 block); zero sums8 ----------
__global__ __launch_bounds__(512) void k_scan2(unsigned* __restrict__ part,
                                               float* __restrict__ sums8) {
    __shared__ unsigned s[512];
    int t = threadIdx.x;
    for (int j = t; j < 2048; j += 512) sums8[j] = 0.f;
    unsigned v = (t < NCHUNK) ? part[t] : 0u;
    s[t] = v;
    __syncthreads();
    for (int o = 1; o < 512; o <<= 1) {
        unsigned add = (t >= o) ? s[t - o] : 0u;
        __syncthreads();
        s[t] += add;
        __syncthreads();
    }
    if (t < NCHUNK) part[t] = s[t] - v;  // exclusive
}

// ---------------- scan step 3: per-chunk exclusive offsets ----------------------
__global__ __launch_bounds__(256) void k_scan3(const unsigned* __restrict__ cnt,
                                               const unsigned* __restrict__ part,
                                               unsigned* __restrict__ off) {
    __shared__ unsigned s[256];
    int i = blockIdx.x * 256 + threadIdx.x;
    int t = threadIdx.x;
    unsigned v = (i < NN) ? cnt[i] : 0u;
    s[t] = v;
    __syncthreads();
    for (int o = 1; o < 256; o <<= 1) {
        unsigned add = (t >= o) ? s[t - o] : 0u;
        __syncthreads();
        s[t] += add;
        __syncthreads();
    }
    if (i < NN) off[i] = part[blockIdx.x] + s[t] - v;  // exclusive
}

// ---- kernel 3: 4-group scatter via packed 16-bit LDS cursors (r9 version) ------
// 256 blocks (1/CU). Cursor word j covers nodes 2j,2j+1; init from 8-bit hist
// prefixes. local counts <= prefix(<=255)+in-chunk(<=~30) << 2^16: no carry.
__global__ __launch_bounds__(512) void k_scatter(const int* __restrict__ ei,
                                                 const unsigned* __restrict__ off,
                                                 const unsigned* __restrict__ hist,
                                                 int* __restrict__ esrc) {
    __shared__ unsigned curs[GSZ4 / 2];  // 50 KB packed
    const int g = blockIdx.x & 3;
    const int t = blockIdx.x >> 2;
    const int lo = g * GSZ4, hi = lo + GSZ4;
    const unsigned* hb = hist + (unsigned)(g * NCH + t) * HSTR;
    for (int j = threadIdx.x; j < GSZ4 / 2; j += 512) {
        unsigned hv = hb[j >> 1];
        unsigned sh = (j & 1) << 4;  // bytes {0,1} or {2,3}
        unsigned p0 = (hv >> sh) & 255u;
        unsigned p1 = (hv >> (sh + 8)) & 255u;
        curs[j] = p0 | (p1 << 16);
    }
    __syncthreads();
    const int end = t * CH + CH;
    for (int i = t * CH + threadIdx.x; i < end; i += 512) {
        int r = __builtin_nontemporal_load(ei + i);
        int c = __builtin_nontemporal_load(ei + NE + i);
        if (r == c || c < lo || c >= hi) continue;
        int q = c - lo;
        unsigned sh = (q & 1) << 4;
        unsigned old = atomicAdd(&curs[q >> 1], 1u << sh);  // LDS atomic
        unsigned pos = off[c] + ((old >> sh) & 0xffffu);
        esrc[pos] = r;  // L2-local slice, plain store
    }
}

// -------- kernel 4: gather bf16 rows: out_c = dc*(dc*x_c + sum dr*x_r) ----------
__global__ __launch_bounds__(256) void k_gather(const unsigned* __restrict__ xh,
                                                const float* __restrict__ dinv,
                                                const unsigned* __restrict__ off,
                                                const unsigned* __restrict__ cnt,
                                                const int* __restrict__ esrc,
                                                float* __restrict__ out) {
    const int lane = threadIdx.x & 63;
    const int wave = threadIdx.x >> 6;
    const int c = blockIdx.x * 4 + wave;
    if (c >= NN) return;

    const float dc = dinv[c];
    unsigned xc = xh[c * 64 + lane];
    float al = dc * __uint_as_float(xc << 16);
    float ah = dc * __uint_as_float(xc & 0xffff0000u);

    const int base = off[c];
    const int n = cnt[c];
    int i = 0;
    for (; i + 8 <= n; i += 8) {
        int   sv[8];
        float wv[8];
        unsigned pv[8];
        #pragma unroll
        for (int j = 0; j < 8; ++j) sv[j] = esrc[base + i + j];
        #pragma unroll
        for (int j = 0; j < 8; ++j) wv[j] = dinv[sv[j]];
        #pragma unroll
        for (int j = 0; j < 8; ++j) pv[j] = xh[sv[j] * 64 + lane];
        #pragma unroll
        for (int j = 0; j < 8; ++j) {
            al = fmaf(wv[j], __uint_as_float(pv[j] << 16), al);
            ah = fmaf(wv[j], __uint_as_float(pv[j] & 0xffff0000u), ah);
        }
    }
    for (; i + 4 <= n; i += 4) {
        int s0 = esrc[base + i], s1 = esrc[base + i + 1];
        int s2 = esrc[base + i + 2], s3 = esrc[base + i + 3];
        float w0 = dinv[s0], w1 = dinv[s1], w2 = dinv[s2], w3 = dinv[s3];
        unsigned p0 = xh[s0 * 64 + lane], p1 = xh[s1 * 64 + lane];
        unsigned p2 = xh[s2 * 64 + lane], p3 = xh[s3 * 64 + lane];
        al = fmaf(w0, __uint_as_float(p0 << 16), al);
        ah = fmaf(w0, __uint_as_float(p0 & 0xffff0000u), ah);
        al = fmaf(w1, __uint_as_float(p1 << 16), al);
        ah = fmaf(w1, __uint_as_float(p1 & 0xffff0000u), ah);
        al = fmaf(w2, __uint_as_float(p2 << 16), al);
        ah = fmaf(w2, __uint_as_float(p2 & 0xffff0000u), ah);
        al = fmaf(w3, __uint_as_float(p3 << 16), al);
        ah = fmaf(w3, __uint_as_float(p3 & 0xffff0000u), ah);
    }
    for (; i < n; ++i) {
        int s0 = esrc[base + i];
        float w0 = dinv[s0];
        unsigned p0 = xh[s0 * 64 + lane];
        al = fmaf(w0, __uint_as_float(p0 << 16), al);
        ah = fmaf(w0, __uint_as_float(p0 & 0xffff0000u), ah);
    }
    al *= dc;
    ah *= dc;
    *(float2*)&out[c * D + 2 * lane] = make_float2(al, ah);
}

// ---- kernel 5: MFMA GEMM + bias + ReLU -> bf16 rh + fused BN partial stats -----
__global__ __launch_bounds__(256, 1) void k_gemm(const float* __restrict__ out,
                                                 unsigned short* __restrict__ rh,
                                                 const unsigned short* __restrict__ Wht,
                                                 const float* __restrict__ b,
                                                 float* __restrict__ sums8) {
    __shared__ float sums_lds[256];
    const int lane = threadIdx.x & 63;
    const int wv = threadIdx.x >> 6;
    const int l15 = lane & 15, l4 = lane >> 4;

    if (threadIdx.x < 256) sums_lds[threadIdx.x] = 0.f;
    __syncthreads();

    short8 bfr[8][4];
    #pragma unroll
    for (int n = 0; n < 8; ++n)
        #pragma unroll
        for (int kk = 0; kk < 4; ++kk)
            bfr[n][kk] = *(const short8*)(Wht + (n * 16 + l15) * D + kk * 32 + l4 * 8);

    float bias8[8];
    #pragma unroll
    for (int n = 0; n < 8; ++n) bias8[n] = b[n * 16 + l15];

    float sl[8], s2l[8];
    #pragma unroll
    for (int n = 0; n < 8; ++n) { sl[n] = 0.f; s2l[n] = 0.f; }

    const int gw = blockIdx.x * 4 + wv;
    #pragma unroll
    for (int t = 0; t < 2; ++t) {
        const int tile = gw * 2 + t;
        if (tile < NN / 16) {
            const int row0 = tile * 16;
            short8 af[4];
            #pragma unroll
            for (int kk = 0; kk < 4; ++kk) {
                const float* ar = out + (row0 + l15) * D + kk * 32 + l4 * 8;
                float4 a0 = *(const float4*)ar;
                float4 a1 = *(const float4*)(ar + 4);
                union { short8 s; unsigned u[4]; } cv;
                cv.u[0] = pk2(a0.x, a0.y);
                cv.u[1] = pk2(a0.z, a0.w);
                cv.u[2] = pk2(a1.x, a1.y);
                cv.u[3] = pk2(a1.z, a1.w);
                af[kk] = cv.s;
            }
            f32x4 acc[8];
            #pragma unroll
            for (int n = 0; n < 8; ++n) acc[n] = (f32x4){0.f, 0.f, 0.f, 0.f};
            #pragma unroll
            for (int n = 0; n < 8; ++n)
                #pragma unroll
                for (int kk = 0; kk < 4; ++kk)
                    acc[n] = __builtin_amdgcn_mfma_f32_16x16x32_bf16(af[kk], bfr[n][kk],
                                                                     acc[n], 0, 0, 0);
            #pragma unroll
            for (int n = 0; n < 8; ++n)
                #pragma unroll
                for (int j = 0; j < 4; ++j) {
                    int row = row0 + l4 * 4 + j;
                    float v = fmaxf(acc[n][j] + bias8[n], 0.f);
                    rh[row * D + n * 16 + l15] = (unsigned short)bf_rne(v);
                    sl[n] += v;
                    s2l[n] = fmaf(v, v, s2l[n]);
                }
        }
    }

    // column reduce: lanes sharing l15 across the 4 l4-groups
    #pragma unroll
    for (int n = 0; n < 8; ++n) {
        float a = sl[n], q = s2l[n];
        a += __shfl_xor(a, 16); a += __shfl_xor(a, 32);
        q += __shfl_xor(q, 16); q += __shfl_xor(q, 32);
        if (l4 == 0) {
            atomicAdd(&sums_lds[n * 16 + l15], a);
            atomicAdd(&sums_lds[128 + n * 16 + l15], q);
        }
    }
    __syncthreads();
    if (threadIdx.x < 256)
        unsafeAtomicAdd(&sums8[(blockIdx.x & 7) * 256 + threadIdx.x],
                        sums_lds[threadIdx.x]);
}

// ------------- kernel 6: out = rh_bf16 * scale + shift (BN affine) --------------
__global__ __launch_bounds__(256) void k_apply(const unsigned* __restrict__ rh,
                                               float* __restrict__ out,
                                               const float* __restrict__ gamma,
                                               const float* __restrict__ beta,
                                               const float* __restrict__ sums8) {
    const float invN = 1.f / (float)NN;
    const int tid = blockIdx.x * blockDim.x + threadIdx.x;
    const int stride = gridDim.x * blockDim.x;
    const int c4 = (tid & 31) * 4;

    float4 s4 = make_float4(0.f, 0.f, 0.f, 0.f);
    float4 q4 = make_float4(0.f, 0.f, 0.f, 0.f);
    #pragma unroll
    for (int k = 0; k < 8; ++k) {
        float4 a = *(const float4*)&sums8[k * 256 + c4];
        float4 q = *(const float4*)&sums8[k * 256 + 128 + c4];
        s4.x += a.x; s4.y += a.y; s4.z += a.z; s4.w += a.w;
        q4.x += q.x; q4.y += q.y; q4.z += q.z; q4.w += q.w;
    }
    float4 g4 = *(const float4*)&gamma[c4];
    float4 be = *(const float4*)&beta[c4];

    float mx = s4.x * invN, my = s4.y * invN, mz = s4.z * invN, mw = s4.w * invN;
    float scx = g4.x * rsqrtf(fmaxf(q4.x * invN - mx * mx, 0.f) + BN_EPS);
    float scy = g4.y * rsqrtf(fmaxf(q4.y * invN - my * my, 0.f) + BN_EPS);
    float scz = g4.z * rsqrtf(fmaxf(q4.z * invN - mz * mz, 0.f) + BN_EPS);
    float scw = g4.w * rsqrtf(fmaxf(q4.w * invN - mw * mw, 0.f) + BN_EPS);
    float shx = be.x - mx * scx, shy = be.y - my * scy;
    float shz = be.z - mz * scz, shw = be.w - mw * scw;

    for (int idx = tid; idx < NN * (D / 4); idx += stride) {
        const int row = idx >> 5;
        uint2 p = *(const uint2*)&rh[row * 64 + (tid & 31) * 2];
        float4 a;
        a.x = __uint_as_float(p.x << 16);
        a.y = __uint_as_float(p.x & 0xffff0000u);
        a.z = __uint_as_float(p.y << 16);
        a.w = __uint_as_float(p.y & 0xffff0000u);
        a.x = a.x * scx + shx;
        a.y = a.y * scy + shy;
        a.z = a.z * scz + shz;
        a.w = a.w * scw + shw;
        ((float4*)out)[idx] = a;
    }
}

extern "C" void kernel_launch(void* const* d_in, const int* in_sizes, int n_in,
                              void* d_out, int out_size, void* d_ws, size_t ws_size,
                              hipStream_t stream) {
    const float* x     = (const float*)d_in[0];
    const int*   ei    = (const int*)d_in[1];
    const float* W     = (const float*)d_in[2];
    const float* b     = (const float*)d_in[3];
    const float* gamma = (const float*)d_in[4];
    const float* beta  = (const float*)d_in[5];
    float*       out   = (float*)d_out;

    char* ws = (char*)d_ws;
    float*          dinv  = (float*)ws;
    unsigned*       cnt   = (unsigned*)(ws + 400000);
    unsigned*       off   = (unsigned*)(ws + 800000);
    unsigned*       part  = (unsigned*)(ws + 1200000);
    float*          sums8 = (float*)(ws + 1202048);
    int*            esrc  = (int*)(ws + 1210368);
    unsigned*       hist  = (unsigned*)(ws + 7610368);   // 12.8 MB
    unsigned*       xh    = (unsigned*)(ws + 20410368);  // 25.6 MB; rh after gather
    unsigned short* Wht   = (unsigned short*)(ws + 46010368);

    k_hist<<<NCH * 4, 512, 0, stream>>>(ei, hist, x, xh);
    k_reduce<<<(4 * HW8 + D * D + 255) / 256, 256, 0, stream>>>(hist, cnt, dinv, W, Wht);
    k_scan1<<<NCHUNK, 256, 0, stream>>>(cnt, part);
    k_scan2<<<1, 512, 0, stream>>>(part, sums8);
    k_scan3<<<NCHUNK, 256, 0, stream>>>(cnt, part, off);
    k_scatter<<<NCH * 4, 512, 0, stream>>>(ei, off, hist, esrc);
    k_gather<<<25000, 256, 0, stream>>>(xh, dinv, off, cnt, esrc, out);
    k_gemm<<<782, 256, 0, stream>>>(out, (unsigned short*)xh, Wht, b, sums8);
    k_apply<<<2048, 256, 0, stream>>>(xh, out, gamma, beta, sums8);
}

// Round 12
// 227.757 us; speedup vs baseline: 1.2358x; 1.1504x over previous
//
#include <hip/hip_runtime.h>
#include <math.h>

#define NN 100000
#define NE 1600000
#define D 128
#define BN_EPS 1e-5f
#define NCHUNK 391   // ceil(NN/256)
#define GSZ4 25000   // hist/scatter group node range (4 groups)
#define NCH 64       // edge chunks
#define CH 25000     // NE / NCH
#define HW8 6250     // words per hist half (4 nodes/word, 8-bit packed)
#define HSTR 12500   // words per (group,chunk) slice: [0,HW8)=cnt, [HW8,2*HW8)=deg

typedef __attribute__((ext_vector_type(8))) short short8;
typedef __attribute__((ext_vector_type(4))) float f32x4;
typedef __attribute__((ext_vector_type(2))) float f32x2;

// ws layout (bytes):
// dinv   [0,        400000)
// cnt    [400000,   800000)
// off    [800000,  1200000)
// part   [1200000, 1202048)
// sums8  [1202048, 1210240)   8 x 256 floats ([0..127]=s, [128..255]=s2)
// esrc   [1210368, 7610368)   src per CSR slot
// hist   [7610368, 20410368)  12.8 MB (4 groups x 64 chunks x 12500 words)
// xh     [20410368,46010368)  x bf16 packed [NN][64] uints; reused as relu-bf16 rh
// Wht    [46010368,46043136)

__device__ __forceinline__ unsigned bf_rne(float f) {
    unsigned u = __float_as_uint(f);
    return (u + 0x7fffu + ((u >> 16) & 1u)) >> 16;
}
__device__ __forceinline__ unsigned pk2(float lo, float hi) {
    return bf_rne(lo) | (bf_rne(hi) << 16);
}

// ---- kernel 1: per-(chunk,group) LDS histograms (8-bit packed), 1024 thr -------
// Grid fixed at 256 blocks (1/CU) by scratch layout -> use 16 waves/block to
// hide edge-stream + LDS-atomic latency.
__global__ __launch_bounds__(1024) void k_hist(const int* __restrict__ ei,
                                               unsigned* __restrict__ hist) {
    __shared__ unsigned loc[HSTR];  // 50 KB
    const int g = blockIdx.x & 3;
    const int t = blockIdx.x >> 2;
    const int lo = g * GSZ4, hi = lo + GSZ4;
    for (int j = threadIdx.x; j < HSTR; j += 1024) loc[j] = 0u;
    __syncthreads();
    const int end = t * CH + CH;
    for (int i = t * CH + threadIdx.x; i < end; i += 1024) {
        int r = __builtin_nontemporal_load(ei + i);
        int c = __builtin_nontemporal_load(ei + NE + i);
        if (r != c) {
            if (c >= lo && c < hi) {
                int q = c - lo;
                atomicAdd(&loc[q >> 2], 1u << ((q & 3) << 3));
            }
            if (r >= lo && r < hi) {
                int q = r - lo;
                atomicAdd(&loc[HW8 + (q >> 2)], 1u << ((q & 3) << 3));
            }
        }
    }
    __syncthreads();
    unsigned* dst = hist + (unsigned)(g * NCH + t) * HSTR;
    for (int j = threadIdx.x; j < HSTR; j += 1024) dst[j] = loc[j];
}

// ---------------- kernel 1b: x -> bf16 packed (standalone, full occupancy) ------
__global__ void k_cvt(const float* __restrict__ x, unsigned* __restrict__ xh) {
    int i = blockIdx.x * blockDim.x + threadIdx.x;
    if (i < NN * 64) {
        f32x2 v = __builtin_nontemporal_load((const f32x2*)x + i);
        xh[i] = pk2(v.x, v.y);
    }
}

// ---- kernel 2: reduce hists -> cnt, dinv; in-place chunk prefixes; + cvtw ------
__global__ __launch_bounds__(256) void k_reduce(unsigned* __restrict__ hist,
                                                unsigned* __restrict__ cnt,
                                                float* __restrict__ dinv,
                                                const float* __restrict__ W,
                                                unsigned short* __restrict__ Wht) {
    int id = blockIdx.x * 256 + threadIdx.x;
    if (id < 4 * HW8) {
        int g = id / HW8;
        int w = id - g * HW8;
        unsigned base = (unsigned)(g * NCH) * HSTR + w;
        unsigned r0 = 0, r1 = 0, r2 = 0, r3 = 0;
        unsigned s0 = 0, s1 = 0, s2 = 0, s3 = 0;
        for (int t = 0; t < NCH; ++t) {
            unsigned idx = base + (unsigned)t * HSTR;
            unsigned v = hist[idx];
            hist[idx] = r0 | (r1 << 8) | (r2 << 16) | (r3 << 24);  // excl prefix
            r0 += v & 255u; r1 += (v >> 8) & 255u;
            r2 += (v >> 16) & 255u; r3 += v >> 24;
            unsigned d = hist[idx + HW8];
            s0 += d & 255u; s1 += (d >> 8) & 255u;
            s2 += (d >> 16) & 255u; s3 += d >> 24;
        }
        int n0 = g * GSZ4 + 4 * w;
        cnt[n0]     = r0; cnt[n0 + 1] = r1; cnt[n0 + 2] = r2; cnt[n0 + 3] = r3;
        dinv[n0]     = rsqrtf((float)(s0 + 1u));  // +1 self-loop
        dinv[n0 + 1] = rsqrtf((float)(s1 + 1u));
        dinv[n0 + 2] = rsqrtf((float)(s2 + 1u));
        dinv[n0 + 3] = rsqrtf((float)(s3 + 1u));
    } else {
        int i = id - 4 * HW8;  // W[k][c] -> Wht[c][k]
        if (i < D * D) {
            int k = i >> 7, c = i & 127;
            Wht[c * D + k] = (unsigned short)bf_rne(W[i]);
        }
    }
}

// ---------------- scan step 1: per-chunk sums -----------------------------------
__global__ __launch_bounds__(256) void k_scan1(const unsigned* __restrict__ cnt,
                                               unsigned* __restrict__ part) {
    __shared__ unsigned s[256];
    int i = blockIdx.x * 256 + threadIdx.x;
    unsigned v = (i < NN) ? cnt[i] : 0u;
    s[threadIdx.x] = v;
    __syncthreads();
    for (int o = 128; o > 0; o >>= 1) {
        if (threadIdx.x < o) s[threadIdx.x] += s[threadIdx.x + o];
        __syncthreads();
    }
    if (threadIdx.x == 0) part[blockIdx.x] = s[0];
}

// ------- scan step 2: exclusive scan of partials (1 block); zero sums8 ----------
__global__ __launch_bounds__(512) void k_scan2(unsigned* __restrict__ part,
                                               float* __restrict__ sums8) {
    __shared__ unsigned s[512];
    int t = threadIdx.x;
    for (int j = t; j < 2048; j += 512) sums8[j] = 0.f;
    unsigned v = (t < NCHUNK) ? part[t] : 0u;
    s[t] = v;
    __syncthreads();
    for (int o = 1; o < 512; o <<= 1) {
        unsigned add = (t >= o) ? s[t - o] : 0u;
        __syncthreads();
        s[t] += add;
        __syncthreads();
    }
    if (t < NCHUNK) part[t] = s[t] - v;  // exclusive
}

// ---------------- scan step 3: per-chunk exclusive offsets ----------------------
__global__ __launch_bounds__(256) void k_scan3(const unsigned* __restrict__ cnt,
                                               const unsigned* __restrict__ part,
                                               unsigned* __restrict__ off) {
    __shared__ unsigned s[256];
    int i = blockIdx.x * 256 + threadIdx.x;
    int t = threadIdx.x;
    unsigned v = (i < NN) ? cnt[i] : 0u;
    s[t] = v;
    __syncthreads();
    for (int o = 1; o < 256; o <<= 1) {
        unsigned add = (t >= o) ? s[t - o] : 0u;
        __syncthreads();
        s[t] += add;
        __syncthreads();
    }
    if (i < NN) off[i] = part[blockIdx.x] + s[t] - v;  // exclusive
}

// ---- kernel 3: 4-group scatter via packed 16-bit LDS cursors, 1024 thr ---------
__global__ __launch_bounds__(1024) void k_scatter(const int* __restrict__ ei,
                                                  const unsigned* __restrict__ off,
                                                  const unsigned* __restrict__ hist,
                                                  int* __restrict__ esrc) {
    __shared__ unsigned curs[GSZ4 / 2];  // 50 KB packed
    const int g = blockIdx.x & 3;
    const int t = blockIdx.x >> 2;
    const int lo = g * GSZ4, hi = lo + GSZ4;
    const unsigned* hb = hist + (unsigned)(g * NCH + t) * HSTR;
    for (int j = threadIdx.x; j < GSZ4 / 2; j += 1024) {
        unsigned hv = hb[j >> 1];
        unsigned sh = (j & 1) << 4;  // bytes {0,1} or {2,3}
        unsigned p0 = (hv >> sh) & 255u;
        unsigned p1 = (hv >> (sh + 8)) & 255u;
        curs[j] = p0 | (p1 << 16);
    }
    __syncthreads();
    const int end = t * CH + CH;
    for (int i = t * CH + threadIdx.x; i < end; i += 1024) {
        int r = __builtin_nontemporal_load(ei + i);
        int c = __builtin_nontemporal_load(ei + NE + i);
        if (r == c || c < lo || c >= hi) continue;
        int q = c - lo;
        unsigned sh = (q & 1) << 4;
        unsigned old = atomicAdd(&curs[q >> 1], 1u << sh);  // LDS atomic
        unsigned pos = off[c] + ((old >> sh) & 0xffffu);
        esrc[pos] = r;  // L2-local slice, plain store
    }
}

// -------- kernel 4: gather bf16 rows: out_c = dc*(dc*x_c + sum dr*x_r) ----------
__global__ __launch_bounds__(256) void k_gather(const unsigned* __restrict__ xh,
                                                const float* __restrict__ dinv,
                                                const unsigned* __restrict__ off,
                                                const unsigned* __restrict__ cnt,
                                                const int* __restrict__ esrc,
                                                float* __restrict__ out) {
    const int lane = threadIdx.x & 63;
    const int wave = threadIdx.x >> 6;
    const int c = blockIdx.x * 4 + wave;
    if (c >= NN) return;

    const float dc = dinv[c];
    unsigned xc = xh[c * 64 + lane];
    float al = dc * __uint_as_float(xc << 16);
    float ah = dc * __uint_as_float(xc & 0xffff0000u);

    const int base = off[c];
    const int n = cnt[c];
    int i = 0;
    for (; i + 8 <= n; i += 8) {
        int   sv[8];
        float wv[8];
        unsigned pv[8];
        #pragma unroll
        for (int j = 0; j < 8; ++j) sv[j] = esrc[base + i + j];
        #pragma unroll
        for (int j = 0; j < 8; ++j) wv[j] = dinv[sv[j]];
        #pragma unroll
        for (int j = 0; j < 8; ++j) pv[j] = xh[sv[j] * 64 + lane];
        #pragma unroll
        for (int j = 0; j < 8; ++j) {
            al = fmaf(wv[j], __uint_as_float(pv[j] << 16), al);
            ah = fmaf(wv[j], __uint_as_float(pv[j] & 0xffff0000u), ah);
        }
    }
    for (; i + 4 <= n; i += 4) {
        int s0 = esrc[base + i], s1 = esrc[base + i + 1];
        int s2 = esrc[base + i + 2], s3 = esrc[base + i + 3];
        float w0 = dinv[s0], w1 = dinv[s1], w2 = dinv[s2], w3 = dinv[s3];
        unsigned p0 = xh[s0 * 64 + lane], p1 = xh[s1 * 64 + lane];
        unsigned p2 = xh[s2 * 64 + lane], p3 = xh[s3 * 64 + lane];
        al = fmaf(w0, __uint_as_float(p0 << 16), al);
        ah = fmaf(w0, __uint_as_float(p0 & 0xffff0000u), ah);
        al = fmaf(w1, __uint_as_float(p1 << 16), al);
        ah = fmaf(w1, __uint_as_float(p1 & 0xffff0000u), ah);
        al = fmaf(w2, __uint_as_float(p2 << 16), al);
        ah = fmaf(w2, __uint_as_float(p2 & 0xffff0000u), ah);
        al = fmaf(w3, __uint_as_float(p3 << 16), al);
        ah = fmaf(w3, __uint_as_float(p3 & 0xffff0000u), ah);
    }
    for (; i < n; ++i) {
        int s0 = esrc[base + i];
        float w0 = dinv[s0];
        unsigned p0 = xh[s0 * 64 + lane];
        al = fmaf(w0, __uint_as_float(p0 << 16), al);
        ah = fmaf(w0, __uint_as_float(p0 & 0xffff0000u), ah);
    }
    al *= dc;
    ah *= dc;
    *(float2*)&out[c * D + 2 * lane] = make_float2(al, ah);
}

// ---- kernel 5: MFMA GEMM + bias + ReLU -> bf16 rh + fused BN partial stats -----
__global__ __launch_bounds__(256, 1) void k_gemm(const float* __restrict__ out,
                                                 unsigned short* __restrict__ rh,
                                                 const unsigned short* __restrict__ Wht,
                                                 const float* __restrict__ b,
                                                 float* __restrict__ sums8) {
    __shared__ float sums_lds[256];
    const int lane = threadIdx.x & 63;
    const int wv = threadIdx.x >> 6;
    const int l15 = lane & 15, l4 = lane >> 4;

    if (threadIdx.x < 256) sums_lds[threadIdx.x] = 0.f;
    __syncthreads();

    short8 bfr[8][4];
    #pragma unroll
    for (int n = 0; n < 8; ++n)
        #pragma unroll
        for (int kk = 0; kk < 4; ++kk)
            bfr[n][kk] = *(const short8*)(Wht + (n * 16 + l15) * D + kk * 32 + l4 * 8);

    float bias8[8];
    #pragma unroll
    for (int n = 0; n < 8; ++n) bias8[n] = b[n * 16 + l15];

    float sl[8], s2l[8];
    #pragma unroll
    for (int n = 0; n < 8; ++n) { sl[n] = 0.f; s2l[n] = 0.f; }

    const int gw = blockIdx.x * 4 + wv;
    #pragma unroll
    for (int t = 0; t < 2; ++t) {
        const int tile = gw * 2 + t;
        if (tile < NN / 16) {
            const int row0 = tile * 16;
            short8 af[4];
            #pragma unroll
            for (int kk = 0; kk < 4; ++kk) {
                const float* ar = out + (row0 + l15) * D + kk * 32 + l4 * 8;
                float4 a0 = *(const float4*)ar;
                float4 a1 = *(const float4*)(ar + 4);
                union { short8 s; unsigned u[4]; } cv;
                cv.u[0] = pk2(a0.x, a0.y);
                cv.u[1] = pk2(a0.z, a0.w);
                cv.u[2] = pk2(a1.x, a1.y);
                cv.u[3] = pk2(a1.z, a1.w);
                af[kk] = cv.s;
            }
            f32x4 acc[8];
            #pragma unroll
            for (int n = 0; n < 8; ++n) acc[n] = (f32x4){0.f, 0.f, 0.f, 0.f};
            #pragma unroll
            for (int n = 0; n < 8; ++n)
                #pragma unroll
                for (int kk = 0; kk < 4; ++kk)
                    acc[n] = __builtin_amdgcn_mfma_f32_16x16x32_bf16(af[kk], bfr[n][kk],
                                                                     acc[n], 0, 0, 0);
            #pragma unroll
            for (int n = 0; n < 8; ++n)
                #pragma unroll
                for (int j = 0; j < 4; ++j) {
                    int row = row0 + l4 * 4 + j;
                    float v = fmaxf(acc[n][j] + bias8[n], 0.f);
                    rh[row * D + n * 16 + l15] = (unsigned short)bf_rne(v);
                    sl[n] += v;
                    s2l[n] = fmaf(v, v, s2l[n]);
                }
        }
    }

    // column reduce: lanes sharing l15 across the 4 l4-groups
    #pragma unroll
    for (int n = 0; n < 8; ++n) {
        float a = sl[n], q = s2l[n];
        a += __shfl_xor(a, 16); a += __shfl_xor(a, 32);
        q += __shfl_xor(q, 16); q += __shfl_xor(q, 32);
        if (l4 == 0) {
            atomicAdd(&sums_lds[n * 16 + l15], a);
            atomicAdd(&sums_lds[128 + n * 16 + l15], q);
        }
    }
    __syncthreads();
    if (threadIdx.x < 256)
        unsafeAtomicAdd(&sums8[(blockIdx.x & 7) * 256 + threadIdx.x],
                        sums_lds[threadIdx.x]);
}

// ------------- kernel 6: out = rh_bf16 * scale + shift (BN affine) --------------
__global__ __launch_bounds__(256) void k_apply(const unsigned* __restrict__ rh,
                                               float* __restrict__ out,
                                               const float* __restrict__ gamma,
                                               const float* __restrict__ beta,
                                               const float* __restrict__ sums8) {
    const float invN = 1.f / (float)NN;
    const int tid = blockIdx.x * blockDim.x + threadIdx.x;
    const int stride = gridDim.x * blockDim.x;
    const int c4 = (tid & 31) * 4;

    float4 s4 = make_float4(0.f, 0.f, 0.f, 0.f);
    float4 q4 = make_float4(0.f, 0.f, 0.f, 0.f);
    #pragma unroll
    for (int k = 0; k < 8; ++k) {
        float4 a = *(const float4*)&sums8[k * 256 + c4];
        float4 q = *(const float4*)&sums8[k * 256 + 128 + c4];
        s4.x += a.x; s4.y += a.y; s4.z += a.z; s4.w += a.w;
        q4.x += q.x; q4.y += q.y; q4.z += q.z; q4.w += q.w;
    }
    float4 g4 = *(const float4*)&gamma[c4];
    float4 be = *(const float4*)&beta[c4];

    float mx = s4.x * invN, my = s4.y * invN, mz = s4.z * invN, mw = s4.w * invN;
    float scx = g4.x * rsqrtf(fmaxf(q4.x * invN - mx * mx, 0.f) + BN_EPS);
    float scy = g4.y * rsqrtf(fmaxf(q4.y * invN - my * my, 0.f) + BN_EPS);
    float scz = g4.z * rsqrtf(fmaxf(q4.z * invN - mz * mz, 0.f) + BN_EPS);
    float scw = g4.w * rsqrtf(fmaxf(q4.w * invN - mw * mw, 0.f) + BN_EPS);
    float shx = be.x - mx * scx, shy = be.y - my * scy;
    float shz = be.z - mz * scz, shw = be.w - mw * scw;

    for (int idx = tid; idx < NN * (D / 4); idx += stride) {
        const int row = idx >> 5;
        uint2 p = *(const uint2*)&rh[row * 64 + (tid & 31) * 2];
        float4 a;
        a.x = __uint_as_float(p.x << 16);
        a.y = __uint_as_float(p.x & 0xffff0000u);
        a.z = __uint_as_float(p.y << 16);
        a.w = __uint_as_float(p.y & 0xffff0000u);
        a.x = a.x * scx + shx;
        a.y = a.y * scy + shy;
        a.z = a.z * scz + shz;
        a.w = a.w * scw + shw;
        ((float4*)out)[idx] = a;
    }
}

extern "C" void kernel_launch(void* const* d_in, const int* in_sizes, int n_in,
                              void* d_out, int out_size, void* d_ws, size_t ws_size,
                              hipStream_t stream) {
    const float* x     = (const float*)d_in[0];
    const int*   ei    = (const int*)d_in[1];
    const float* W     = (const float*)d_in[2];
    const float* b     = (const float*)d_in[3];
    const float* gamma = (const float*)d_in[4];
    const float* beta  = (const float*)d_in[5];
    float*       out   = (float*)d_out;

    char* ws = (char*)d_ws;
    float*          dinv  = (float*)ws;
    unsigned*       cnt   = (unsigned*)(ws + 400000);
    unsigned*       off   = (unsigned*)(ws + 800000);
    unsigned*       part  = (unsigned*)(ws + 1200000);
    float*          sums8 = (float*)(ws + 1202048);
    int*            esrc  = (int*)(ws + 1210368);
    unsigned*       hist  = (unsigned*)(ws + 7610368);   // 12.8 MB
    unsigned*       xh    = (unsigned*)(ws + 20410368);  // 25.6 MB; rh after gather
    unsigned short* Wht   = (unsigned short*)(ws + 46010368);

    k_hist<<<NCH * 4, 1024, 0, stream>>>(ei, hist);
    k_cvt<<<25000, 256, 0, stream>>>(x, xh);
    k_reduce<<<(4 * HW8 + D * D + 255) / 256, 256, 0, stream>>>(hist, cnt, dinv, W, Wht);
    k_scan1<<<NCHUNK, 256, 0, stream>>>(cnt, part);
    k_scan2<<<1, 512, 0, stream>>>(part, sums8);
    k_scan3<<<NCHUNK, 256, 0, stream>>>(cnt, part, off);
    k_scatter<<<NCH * 4, 1024, 0, stream>>>(ei, off, hist, esrc);
    k_gather<<<25000, 256, 0, stream>>>(xh, dinv, off, cnt, esrc, out);
    k_gemm<<<782, 256, 0, stream>>>(out, (unsigned short*)xh, Wht, b, sums8);
    k_apply<<<2048, 256, 0, stream>>>(xh, out, gamma, beta, sums8);
}

// Round 13
// 211.999 us; speedup vs baseline: 1.3277x; 1.0743x over previous
//
#include <hip/hip_runtime.h>
#include <math.h>

#define NN 100000
#define NE 1600000
#define D 128
#define BN_EPS 1e-5f
#define GSZ4 25000   // hist/scatter group node range (4 groups)
#define NCH 64       // edge chunks
#define CH 25000     // NE / NCH
#define HW8 6250     // words per hist half (4 nodes/word, 8-bit packed)
#define HSTR 12500   // words per (group,chunk) slice: [0,HW8)=cnt, [HW8,2*HW8)=deg
#define NPART 98     // ceil(NN/1024) part chunks (1024 nodes per reduce/scan3 block)

typedef __attribute__((ext_vector_type(8))) short short8;
typedef __attribute__((ext_vector_type(4))) float f32x4;

// ws layout (bytes):
// dinv   [0,        400000)
// cnt    [400000,   800000)
// off    [800000,  1200000)
// part   [1200000, 1202048)
// sums8  [1202048, 1210240)   8 x 256 floats ([0..127]=s, [128..255]=s2)
// esrc   [1210368, 7610368)   src per CSR slot
// hist   [7610368, 20410368)  12.8 MB (4 groups x 64 chunks x 12500 words)
// xh     [20410368,46010368)  x bf16 packed [NN][64] uints; reused as relu-bf16 rh
// Wht    [46010368,46043136)
// d_out doubles as bf16 agg buffer [NN][64] uints (first 25.6 MB) between
// gather and gemm; apply overwrites all of d_out at the end.

__device__ __forceinline__ unsigned bf_rne(float f) {
    unsigned u = __float_as_uint(f);
    return (u + 0x7fffu + ((u >> 16) & 1u)) >> 16;
}
__device__ __forceinline__ unsigned pk2(float lo, float hi) {
    return bf_rne(lo) | (bf_rne(hi) << 16);
}

// ---- kernel 1: per-(chunk,group) LDS histograms (8-bit packed), 1024 thr -------
__global__ __launch_bounds__(1024) void k_hist(const int* __restrict__ ei,
                                               unsigned* __restrict__ hist) {
    __shared__ unsigned loc[HSTR];  // 50 KB
    const int g = blockIdx.x & 3;
    const int t = blockIdx.x >> 2;
    const int lo = g * GSZ4, hi = lo + GSZ4;
    for (int j = threadIdx.x; j < HSTR; j += 1024) loc[j] = 0u;
    __syncthreads();
    const int end = t * CH + CH;
    for (int i = t * CH + threadIdx.x; i < end; i += 1024) {
        int r = __builtin_nontemporal_load(ei + i);
        int c = __builtin_nontemporal_load(ei + NE + i);
        if (r != c) {
            if (c >= lo && c < hi) {
                int q = c - lo;
                atomicAdd(&loc[q >> 2], 1u << ((q & 3) << 3));
            }
            if (r >= lo && r < hi) {
                int q = r - lo;
                atomicAdd(&loc[HW8 + (q >> 2)], 1u << ((q & 3) << 3));
            }
        }
    }
    __syncthreads();
    unsigned* dst = hist + (unsigned)(g * NCH + t) * HSTR;
    for (int j = threadIdx.x; j < HSTR; j += 1024) dst[j] = loc[j];
}

// ------------- kernel 1b: x -> bf16 packed, f32x4 (16B) loads -------------------
__global__ void k_cvt(const float* __restrict__ x, unsigned* __restrict__ xh) {
    int i = blockIdx.x * blockDim.x + threadIdx.x;  // one f32x4 -> uint2
    if (i < NN * 32) {
        f32x4 v = __builtin_nontemporal_load((const f32x4*)x + i);
        uint2 o;
        o.x = pk2(v.x, v.y);
        o.y = pk2(v.z, v.w);
        ((uint2*)xh)[i] = o;
    }
}

// ---- kernel 2: reduce hists -> cnt, dinv; chunk prefixes; scan1; cvtw ----------
// Blocks 0..97: ids 0..24999 (node = 4*id) + block-reduce of cnt sums -> part.
// Blocks 98..161: cvtw (W[k][c] -> Wht[c][k]).
__global__ __launch_bounds__(256) void k_reduce(unsigned* __restrict__ hist,
                                                unsigned* __restrict__ cnt,
                                                float* __restrict__ dinv,
                                                const float* __restrict__ W,
                                                unsigned short* __restrict__ Wht,
                                                unsigned* __restrict__ part) {
    __shared__ unsigned ps[256];
    int id = blockIdx.x * 256 + threadIdx.x;
    unsigned mysum = 0;
    if (id < 4 * HW8) {
        int g = id / HW8;
        int w = id - g * HW8;
        unsigned base = (unsigned)(g * NCH) * HSTR + w;
        unsigned r0 = 0, r1 = 0, r2 = 0, r3 = 0;
        unsigned s0 = 0, s1 = 0, s2 = 0, s3 = 0;
        for (int t = 0; t < NCH; ++t) {
            unsigned idx = base + (unsigned)t * HSTR;
            unsigned v = hist[idx];
            hist[idx] = r0 | (r1 << 8) | (r2 << 16) | (r3 << 24);  // excl prefix
            r0 += v & 255u; r1 += (v >> 8) & 255u;
            r2 += (v >> 16) & 255u; r3 += v >> 24;
            unsigned d = hist[idx + HW8];
            s0 += d & 255u; s1 += (d >> 8) & 255u;
            s2 += (d >> 16) & 255u; s3 += d >> 24;
        }
        int n0 = 4 * id;
        cnt[n0]     = r0; cnt[n0 + 1] = r1; cnt[n0 + 2] = r2; cnt[n0 + 3] = r3;
        dinv[n0]     = rsqrtf((float)(s0 + 1u));  // +1 self-loop
        dinv[n0 + 1] = rsqrtf((float)(s1 + 1u));
        dinv[n0 + 2] = rsqrtf((float)(s2 + 1u));
        dinv[n0 + 3] = rsqrtf((float)(s3 + 1u));
        mysum = r0 + r1 + r2 + r3;
    } else {
        int i = id - 4 * HW8;  // cvtw
        if (i < D * D) {
            int k = i >> 7, c = i & 127;
            Wht[c * D + k] = (unsigned short)bf_rne(W[i]);
        }
    }
    if (blockIdx.x < NPART) {  // scan1: per-1024-node chunk sums
        ps[threadIdx.x] = mysum;
        __syncthreads();
        for (int o = 128; o > 0; o >>= 1) {
            if (threadIdx.x < o) ps[threadIdx.x] += ps[threadIdx.x + o];
            __syncthreads();
        }
        if (threadIdx.x == 0) part[blockIdx.x] = ps[0];
    }
}

// ------- scan step 2: exclusive scan of NPART partials; zero sums8 --------------
__global__ __launch_bounds__(512) void k_scan2(unsigned* __restrict__ part,
                                               float* __restrict__ sums8) {
    __shared__ unsigned s[512];
    int t = threadIdx.x;
    for (int j = t; j < 2048; j += 512) sums8[j] = 0.f;
    unsigned v = (t < NPART) ? part[t] : 0u;
    s[t] = v;
    __syncthreads();
    for (int o = 1; o < 512; o <<= 1) {
        unsigned add = (t >= o) ? s[t - o] : 0u;
        __syncthreads();
        s[t] += add;
        __syncthreads();
    }
    if (t < NPART) part[t] = s[t] - v;  // exclusive
}

// ------- scan step 3: per-node exclusive offsets (4 nodes/thread) ---------------
__global__ __launch_bounds__(256) void k_scan3(const unsigned* __restrict__ cnt,
                                               const unsigned* __restrict__ part,
                                               unsigned* __restrict__ off) {
    __shared__ unsigned s[256];
    const int t = threadIdx.x;
    const int n0 = (blockIdx.x * 256 + t) * 4;
    unsigned c0 = 0, c1 = 0, c2 = 0, c3 = 0;
    if (n0 + 3 < NN) {
        uint4 v = *(const uint4*)&cnt[n0];
        c0 = v.x; c1 = v.y; c2 = v.z; c3 = v.w;
    } else if (n0 < NN) {
        c0 = cnt[n0];
        if (n0 + 1 < NN) c1 = cnt[n0 + 1];
        if (n0 + 2 < NN) c2 = cnt[n0 + 2];
    }
    unsigned mysum = c0 + c1 + c2 + c3;
    s[t] = mysum;
    __syncthreads();
    for (int o = 1; o < 256; o <<= 1) {
        unsigned add = (t >= o) ? s[t - o] : 0u;
        __syncthreads();
        s[t] += add;
        __syncthreads();
    }
    unsigned e = part[blockIdx.x] + s[t] - mysum;
    if (n0 < NN) {
        off[n0] = e;
        if (n0 + 1 < NN) off[n0 + 1] = e + c0;
        if (n0 + 2 < NN) off[n0 + 2] = e + c0 + c1;
        if (n0 + 3 < NN) off[n0 + 3] = e + c0 + c1 + c2;
    }
}

// ---- kernel 3: 4-group scatter via packed 16-bit LDS cursors, 1024 thr ---------
__global__ __launch_bounds__(1024) void k_scatter(const int* __restrict__ ei,
                                                  const unsigned* __restrict__ off,
                                                  const unsigned* __restrict__ hist,
                                                  int* __restrict__ esrc) {
    __shared__ unsigned curs[GSZ4 / 2];  // 50 KB packed
    const int g = blockIdx.x & 3;
    const int t = blockIdx.x >> 2;
    const int lo = g * GSZ4, hi = lo + GSZ4;
    const unsigned* hb = hist + (unsigned)(g * NCH + t) * HSTR;
    for (int j = threadIdx.x; j < GSZ4 / 2; j += 1024) {
        unsigned hv = hb[j >> 1];
        unsigned sh = (j & 1) << 4;  // bytes {0,1} or {2,3}
        unsigned p0 = (hv >> sh) & 255u;
        unsigned p1 = (hv >> (sh + 8)) & 255u;
        curs[j] = p0 | (p1 << 16);
    }
    __syncthreads();
    const int end = t * CH + CH;
    for (int i = t * CH + threadIdx.x; i < end; i += 1024) {
        int r = __builtin_nontemporal_load(ei + i);
        int c = __builtin_nontemporal_load(ei + NE + i);
        if (r == c || c < lo || c >= hi) continue;
        int q = c - lo;
        unsigned sh = (q & 1) << 4;
        unsigned old = atomicAdd(&curs[q >> 1], 1u << sh);  // LDS atomic
        unsigned pos = off[c] + ((old >> sh) & 0xffffu);
        esrc[pos] = r;  // L2-local slice, plain store
    }
}

// -------- kernel 4: gather bf16 rows -> bf16 agg: dc*(dc*x_c + sum dr*x_r) ------
__global__ __launch_bounds__(256) void k_gather(const unsigned* __restrict__ xh,
                                                const float* __restrict__ dinv,
                                                const unsigned* __restrict__ off,
                                                const unsigned* __restrict__ cnt,
                                                const int* __restrict__ esrc,
                                                unsigned* __restrict__ outh) {
    const int lane = threadIdx.x & 63;
    const int wave = threadIdx.x >> 6;
    const int c = blockIdx.x * 4 + wave;
    if (c >= NN) return;

    const float dc = dinv[c];
    unsigned xc = xh[c * 64 + lane];
    float al = dc * __uint_as_float(xc << 16);
    float ah = dc * __uint_as_float(xc & 0xffff0000u);

    const int base = off[c];
    const int n = cnt[c];
    int i = 0;
    for (; i + 8 <= n; i += 8) {
        int   sv[8];
        float wv[8];
        unsigned pv[8];
        #pragma unroll
        for (int j = 0; j < 8; ++j) sv[j] = esrc[base + i + j];
        #pragma unroll
        for (int j = 0; j < 8; ++j) wv[j] = dinv[sv[j]];
        #pragma unroll
        for (int j = 0; j < 8; ++j) pv[j] = xh[sv[j] * 64 + lane];
        #pragma unroll
        for (int j = 0; j < 8; ++j) {
            al = fmaf(wv[j], __uint_as_float(pv[j] << 16), al);
            ah = fmaf(wv[j], __uint_as_float(pv[j] & 0xffff0000u), ah);
        }
    }
    for (; i + 4 <= n; i += 4) {
        int s0 = esrc[base + i], s1 = esrc[base + i + 1];
        int s2 = esrc[base + i + 2], s3 = esrc[base + i + 3];
        float w0 = dinv[s0], w1 = dinv[s1], w2 = dinv[s2], w3 = dinv[s3];
        unsigned p0 = xh[s0 * 64 + lane], p1 = xh[s1 * 64 + lane];
        unsigned p2 = xh[s2 * 64 + lane], p3 = xh[s3 * 64 + lane];
        al = fmaf(w0, __uint_as_float(p0 << 16), al);
        ah = fmaf(w0, __uint_as_float(p0 & 0xffff0000u), ah);
        al = fmaf(w1, __uint_as_float(p1 << 16), al);
        ah = fmaf(w1, __uint_as_float(p1 & 0xffff0000u), ah);
        al = fmaf(w2, __uint_as_float(p2 << 16), al);
        ah = fmaf(w2, __uint_as_float(p2 & 0xffff0000u), ah);
        al = fmaf(w3, __uint_as_float(p3 << 16), al);
        ah = fmaf(w3, __uint_as_float(p3 & 0xffff0000u), ah);
    }
    for (; i < n; ++i) {
        int s0 = esrc[base + i];
        float w0 = dinv[s0];
        unsigned p0 = xh[s0 * 64 + lane];
        al = fmaf(w0, __uint_as_float(p0 << 16), al);
        ah = fmaf(w0, __uint_as_float(p0 & 0xffff0000u), ah);
    }
    outh[c * 64 + lane] = pk2(al * dc, ah * dc);  // bf16 agg (same rounding gemm did)
}

// ---- kernel 5: MFMA GEMM (bf16 A direct) + bias + ReLU -> bf16 rh + BN stats ---
__global__ __launch_bounds__(256, 1) void k_gemm(const unsigned short* __restrict__ aggh,
                                                 unsigned short* __restrict__ rh,
                                                 const unsigned short* __restrict__ Wht,
                                                 const float* __restrict__ b,
                                                 float* __restrict__ sums8) {
    __shared__ float sums_lds[256];
    const int lane = threadIdx.x & 63;
    const int wv = threadIdx.x >> 6;
    const int l15 = lane & 15, l4 = lane >> 4;

    if (threadIdx.x < 256) sums_lds[threadIdx.x] = 0.f;
    __syncthreads();

    short8 bfr[8][4];
    #pragma unroll
    for (int n = 0; n < 8; ++n)
        #pragma unroll
        for (int kk = 0; kk < 4; ++kk)
            bfr[n][kk] = *(const short8*)(Wht + (n * 16 + l15) * D + kk * 32 + l4 * 8);

    float bias8[8];
    #pragma unroll
    for (int n = 0; n < 8; ++n) bias8[n] = b[n * 16 + l15];

    float sl[8], s2l[8];
    #pragma unroll
    for (int n = 0; n < 8; ++n) { sl[n] = 0.f; s2l[n] = 0.f; }

    const int gw = blockIdx.x * 4 + wv;
    #pragma unroll
    for (int t = 0; t < 2; ++t) {
        const int tile = gw * 2 + t;
        if (tile < NN / 16) {
            const int row0 = tile * 16;
            short8 af[4];
            #pragma unroll
            for (int kk = 0; kk < 4; ++kk)
                af[kk] = *(const short8*)(aggh + (row0 + l15) * D + kk * 32 + l4 * 8);
            f32x4 acc[8];
            #pragma unroll
            for (int n = 0; n < 8; ++n) acc[n] = (f32x4){0.f, 0.f, 0.f, 0.f};
            #pragma unroll
            for (int n = 0; n < 8; ++n)
                #pragma unroll
                for (int kk = 0; kk < 4; ++kk)
                    acc[n] = __builtin_amdgcn_mfma_f32_16x16x32_bf16(af[kk], bfr[n][kk],
                                                                     acc[n], 0, 0, 0);
            #pragma unroll
            for (int n = 0; n < 8; ++n)
                #pragma unroll
                for (int j = 0; j < 4; ++j) {
                    int row = row0 + l4 * 4 + j;
                    float v = fmaxf(acc[n][j] + bias8[n], 0.f);
                    rh[row * D + n * 16 + l15] = (unsigned short)bf_rne(v);
                    sl[n] += v;
                    s2l[n] = fmaf(v, v, s2l[n]);
                }
        }
    }

    // column reduce: lanes sharing l15 across the 4 l4-groups
    #pragma unroll
    for (int n = 0; n < 8; ++n) {
        float a = sl[n], q = s2l[n];
        a += __shfl_xor(a, 16); a += __shfl_xor(a, 32);
        q += __shfl_xor(q, 16); q += __shfl_xor(q, 32);
        if (l4 == 0) {
            atomicAdd(&sums_lds[n * 16 + l15], a);
            atomicAdd(&sums_lds[128 + n * 16 + l15], q);
        }
    }
    __syncthreads();
    if (threadIdx.x < 256)
        unsafeAtomicAdd(&sums8[(blockIdx.x & 7) * 256 + threadIdx.x],
                        sums_lds[threadIdx.x]);
}

// ------------- kernel 6: out = rh_bf16 * scale + shift (BN affine) --------------
__global__ __launch_bounds__(256) void k_apply(const unsigned* __restrict__ rh,
                                               float* __restrict__ out,
                                               const float* __restrict__ gamma,
                                               const float* __restrict__ beta,
                                               const float* __restrict__ sums8) {
    const float invN = 1.f / (float)NN;
    const int tid = blockIdx.x * blockDim.x + threadIdx.x;
    const int stride = gridDim.x * blockDim.x;
    const int c4 = (tid & 31) * 4;

    float4 s4 = make_float4(0.f, 0.f, 0.f, 0.f);
    float4 q4 = make_float4(0.f, 0.f, 0.f, 0.f);
    #pragma unroll
    for (int k = 0; k < 8; ++k) {
        float4 a = *(const float4*)&sums8[k * 256 + c4];
        float4 q = *(const float4*)&sums8[k * 256 + 128 + c4];
        s4.x += a.x; s4.y += a.y; s4.z += a.z; s4.w += a.w;
        q4.x += q.x; q4.y += q.y; q4.z += q.z; q4.w += q.w;
    }
    float4 g4 = *(const float4*)&gamma[c4];
    float4 be = *(const float4*)&beta[c4];

    float mx = s4.x * invN, my = s4.y * invN, mz = s4.z * invN, mw = s4.w * invN;
    float scx = g4.x * rsqrtf(fmaxf(q4.x * invN - mx * mx, 0.f) + BN_EPS);
    float scy = g4.y * rsqrtf(fmaxf(q4.y * invN - my * my, 0.f) + BN_EPS);
    float scz = g4.z * rsqrtf(fmaxf(q4.z * invN - mz * mz, 0.f) + BN_EPS);
    float scw = g4.w * rsqrtf(fmaxf(q4.w * invN - mw * mw, 0.f) + BN_EPS);
    float shx = be.x - mx * scx, shy = be.y - my * scy;
    float shz = be.z - mz * scz, shw = be.w - mw * scw;

    for (int idx = tid; idx < NN * (D / 4); idx += stride) {
        const int row = idx >> 5;
        uint2 p = *(const uint2*)&rh[row * 64 + (tid & 31) * 2];
        float4 a;
        a.x = __uint_as_float(p.x << 16);
        a.y = __uint_as_float(p.x & 0xffff0000u);
        a.z = __uint_as_float(p.y << 16);
        a.w = __uint_as_float(p.y & 0xffff0000u);
        a.x = a.x * scx + shx;
        a.y = a.y * scy + shy;
        a.z = a.z * scz + shz;
        a.w = a.w * scw + shw;
        ((float4*)out)[idx] = a;
    }
}

extern "C" void kernel_launch(void* const* d_in, const int* in_sizes, int n_in,
                              void* d_out, int out_size, void* d_ws, size_t ws_size,
                              hipStream_t stream) {
    const float* x     = (const float*)d_in[0];
    const int*   ei    = (const int*)d_in[1];
    const float* W     = (const float*)d_in[2];
    const float* b     = (const float*)d_in[3];
    const float* gamma = (const float*)d_in[4];
    const float* beta  = (const float*)d_in[5];
    float*       out   = (float*)d_out;

    char* ws = (char*)d_ws;
    float*          dinv  = (float*)ws;
    unsigned*       cnt   = (unsigned*)(ws + 400000);
    unsigned*       off   = (unsigned*)(ws + 800000);
    unsigned*       part  = (unsigned*)(ws + 1200000);
    float*          sums8 = (float*)(ws + 1202048);
    int*            esrc  = (int*)(ws + 1210368);
    unsigned*       hist  = (unsigned*)(ws + 7610368);   // 12.8 MB
    unsigned*       xh    = (unsigned*)(ws + 20410368);  // 25.6 MB; rh after gather
    unsigned short* Wht   = (unsigned short*)(ws + 46010368);

    k_hist<<<NCH * 4, 1024, 0, stream>>>(ei, hist);
    k_cvt<<<(NN * 32 + 255) / 256, 256, 0, stream>>>(x, xh);
    k_reduce<<<(4 * HW8 + D * D + 255) / 256, 256, 0, stream>>>(hist, cnt, dinv, W, Wht, part);
    k_scan2<<<1, 512, 0, stream>>>(part, sums8);
    k_scan3<<<NPART, 256, 0, stream>>>(cnt, part, off);
    k_scatter<<<NCH * 4, 1024, 0, stream>>>(ei, off, hist, esrc);
    k_gather<<<25000, 256, 0, stream>>>(xh, dinv, off, cnt, esrc, (unsigned*)out);
    k_gemm<<<782, 256, 0, stream>>>((const unsigned short*)out, (unsigned short*)xh, Wht, b, sums8);
    k_apply<<<2048, 256, 0, stream>>>(xh, out, gamma, beta, sums8);
}

// Round 14
// 202.448 us; speedup vs baseline: 1.3903x; 1.0472x over previous
//
#include <hip/hip_runtime.h>
#include <math.h>

#define NN 100000
#define NE 1600000
#define D 128
#define BN_EPS 1e-5f
#define GSZ4 25000   // hist/scatter group node range (4 groups)
#define NCH 64       // edge chunks
#define CH 25000     // NE / NCH
#define HW8 6250     // words per hist half (4 nodes/word, 8-bit packed)
#define HSTR 12500   // words per (group,chunk) slice: [0,HW8)=cnt, [HW8,2*HW8)=deg
#define NPART 98     // ceil(NN/1024) part chunks
#define NCVT 192     // extra hist-kernel blocks doing x->bf16

typedef __attribute__((ext_vector_type(8))) short short8;
typedef __attribute__((ext_vector_type(4))) float f32x4;

// ws layout (bytes):
// dinv   [0,        400000)
// cnt    [400000,   800000)
// off    [800000,  1200000)
// part   [1200000, 1202048)
// sums8  [1202048, 1210240)   8 x 256 floats ([0..127]=s, [128..255]=s2)
// esrc   [1210368, 7610368)   src per CSR slot
// hist   [7610368, 20410368)  12.8 MB (4 groups x 64 chunks x 12500 words)
// xh     [20410368,46010368)  x bf16 packed [NN][64] uints; reused as relu-bf16 rh
// Wht    [46010368,46043136)
// d_out doubles as bf16 agg buffer between gather and gemm.

__device__ __forceinline__ unsigned bf_rne(float f) {
    unsigned u = __float_as_uint(f);
    return (u + 0x7fffu + ((u >> 16) & 1u)) >> 16;
}
__device__ __forceinline__ unsigned pk2(float lo, float hi) {
    return bf_rne(lo) | (bf_rne(hi) << 16);
}

// ---- kernel 1: heterogeneous: blocks<256 LDS histograms; blocks>=256 x->bf16 ----
__global__ __launch_bounds__(1024) void k_hist(const int* __restrict__ ei,
                                               unsigned* __restrict__ hist,
                                               const float* __restrict__ x,
                                               unsigned* __restrict__ xh) {
    __shared__ unsigned loc[HSTR];  // 50 KB
    if (blockIdx.x < 256) {
        const int g = blockIdx.x & 3;
        const int t = blockIdx.x >> 2;
        const int lo = g * GSZ4, hi = lo + GSZ4;
        for (int j = threadIdx.x; j < HSTR; j += 1024) loc[j] = 0u;
        __syncthreads();
        const int end = t * CH + CH;
        for (int i = t * CH + threadIdx.x; i < end; i += 1024) {
            int r = __builtin_nontemporal_load(ei + i);
            int c = __builtin_nontemporal_load(ei + NE + i);
            if (r != c) {
                if (c >= lo && c < hi) {
                    int q = c - lo;
                    atomicAdd(&loc[q >> 2], 1u << ((q & 3) << 3));
                }
                if (r >= lo && r < hi) {
                    int q = r - lo;
                    atomicAdd(&loc[HW8 + (q >> 2)], 1u << ((q & 3) << 3));
                }
            }
        }
        __syncthreads();
        unsigned* dst = hist + (unsigned)(g * NCH + t) * HSTR;
        for (int j = threadIdx.x; j < HSTR; j += 1024) dst[j] = loc[j];
    } else {
        // x -> bf16 packed, f32x4 (16B) loads, grid-stride
        int idx = (blockIdx.x - 256) * 1024 + threadIdx.x;
        const int stride = NCVT * 1024;
        for (; idx < NN * 32; idx += stride) {
            f32x4 v = __builtin_nontemporal_load((const f32x4*)x + idx);
            uint2 o;
            o.x = pk2(v.x, v.y);
            o.y = pk2(v.z, v.w);
            ((uint2*)xh)[idx] = o;
        }
    }
}

// ---- kernel 2: reduce hists -> cnt, dinv; chunk prefixes; scan1; cvtw; zero ----
// Blocks 0..97: ids 0..24999 (node = 4*id) + block-reduce of cnt sums -> part.
// Remaining blocks: cvtw (W -> Wht) and sums8 zeroing.
__global__ __launch_bounds__(256) void k_reduce(unsigned* __restrict__ hist,
                                                unsigned* __restrict__ cnt,
                                                float* __restrict__ dinv,
                                                const float* __restrict__ W,
                                                unsigned short* __restrict__ Wht,
                                                unsigned* __restrict__ part,
                                                float* __restrict__ sums8) {
    __shared__ unsigned ps[256];
    int id = blockIdx.x * 256 + threadIdx.x;
    unsigned mysum = 0;
    if (id < 4 * HW8) {
        int g = id / HW8;
        int w = id - g * HW8;
        unsigned base = (unsigned)(g * NCH) * HSTR + w;
        unsigned r0 = 0, r1 = 0, r2 = 0, r3 = 0;
        unsigned s0 = 0, s1 = 0, s2 = 0, s3 = 0;
        for (int t = 0; t < NCH; ++t) {
            unsigned idx = base + (unsigned)t * HSTR;
            unsigned v = hist[idx];
            hist[idx] = r0 | (r1 << 8) | (r2 << 16) | (r3 << 24);  // excl prefix
            r0 += v & 255u; r1 += (v >> 8) & 255u;
            r2 += (v >> 16) & 255u; r3 += v >> 24;
            unsigned d = hist[idx + HW8];
            s0 += d & 255u; s1 += (d >> 8) & 255u;
            s2 += (d >> 16) & 255u; s3 += d >> 24;
        }
        int n0 = 4 * id;
        cnt[n0]     = r0; cnt[n0 + 1] = r1; cnt[n0 + 2] = r2; cnt[n0 + 3] = r3;
        dinv[n0]     = rsqrtf((float)(s0 + 1u));  // +1 self-loop
        dinv[n0 + 1] = rsqrtf((float)(s1 + 1u));
        dinv[n0 + 2] = rsqrtf((float)(s2 + 1u));
        dinv[n0 + 3] = rsqrtf((float)(s3 + 1u));
        mysum = r0 + r1 + r2 + r3;
    } else {
        int i = id - 4 * HW8;
        if (i < D * D) {           // cvtw: W[k][c] -> Wht[c][k]
            int k = i >> 7, c = i & 127;
            Wht[c * D + k] = (unsigned short)bf_rne(W[i]);
        } else if (i < D * D + 2048) {
            sums8[i - D * D] = 0.f;
        }
    }
    if (blockIdx.x < NPART) {  // scan1: per-1024-node chunk sums
        ps[threadIdx.x] = mysum;
        __syncthreads();
        for (int o = 128; o > 0; o >>= 1) {
            if (threadIdx.x < o) ps[threadIdx.x] += ps[threadIdx.x + o];
            __syncthreads();
        }
        if (threadIdx.x == 0) part[blockIdx.x] = ps[0];
    }
}

// ------- scan step: per-node exclusive offsets; each block scans part itself ----
__global__ __launch_bounds__(256) void k_scan3(const unsigned* __restrict__ cnt,
                                               const unsigned* __restrict__ part,
                                               unsigned* __restrict__ off) {
    __shared__ unsigned pp[128];
    __shared__ unsigned s[256];
    const int t = threadIdx.x;
    if (t < 128) pp[t] = (t < NPART) ? part[t] : 0u;
    __syncthreads();
    for (int o = 1; o < 128; o <<= 1) {  // inclusive scan of partials
        unsigned add = (t < 128 && t >= o) ? pp[t - o] : 0u;
        __syncthreads();
        if (t < 128) pp[t] += add;
        __syncthreads();
    }
    const unsigned base = (blockIdx.x == 0) ? 0u : pp[blockIdx.x - 1];

    const int n0 = (blockIdx.x * 256 + t) * 4;
    unsigned c0 = 0, c1 = 0, c2 = 0, c3 = 0;
    if (n0 + 3 < NN) {
        uint4 v = *(const uint4*)&cnt[n0];
        c0 = v.x; c1 = v.y; c2 = v.z; c3 = v.w;
    } else if (n0 < NN) {
        c0 = cnt[n0];
        if (n0 + 1 < NN) c1 = cnt[n0 + 1];
        if (n0 + 2 < NN) c2 = cnt[n0 + 2];
    }
    unsigned mysum = c0 + c1 + c2 + c3;
    s[t] = mysum;
    __syncthreads();
    for (int o = 1; o < 256; o <<= 1) {
        unsigned add = (t >= o) ? s[t - o] : 0u;
        __syncthreads();
        s[t] += add;
        __syncthreads();
    }
    unsigned e = base + s[t] - mysum;
    if (n0 < NN) {
        off[n0] = e;
        if (n0 + 1 < NN) off[n0 + 1] = e + c0;
        if (n0 + 2 < NN) off[n0 + 2] = e + c0 + c1;
        if (n0 + 3 < NN) off[n0 + 3] = e + c0 + c1 + c2;
    }
}

// ---- kernel 3: 4-group scatter via packed 16-bit LDS cursors, 1024 thr ---------
__global__ __launch_bounds__(1024) void k_scatter(const int* __restrict__ ei,
                                                  const unsigned* __restrict__ off,
                                                  const unsigned* __restrict__ hist,
                                                  int* __restrict__ esrc) {
    __shared__ unsigned curs[GSZ4 / 2];  // 50 KB packed
    const int g = blockIdx.x & 3;
    const int t = blockIdx.x >> 2;
    const int lo = g * GSZ4, hi = lo + GSZ4;
    const unsigned* hb = hist + (unsigned)(g * NCH + t) * HSTR;
    for (int j = threadIdx.x; j < GSZ4 / 2; j += 1024) {
        unsigned hv = hb[j >> 1];
        unsigned sh = (j & 1) << 4;  // bytes {0,1} or {2,3}
        unsigned p0 = (hv >> sh) & 255u;
        unsigned p1 = (hv >> (sh + 8)) & 255u;
        curs[j] = p0 | (p1 << 16);
    }
    __syncthreads();
    const int end = t * CH + CH;
    for (int i = t * CH + threadIdx.x; i < end; i += 1024) {
        int r = __builtin_nontemporal_load(ei + i);
        int c = __builtin_nontemporal_load(ei + NE + i);
        if (r == c || c < lo || c >= hi) continue;
        int q = c - lo;
        unsigned sh = (q & 1) << 4;
        unsigned old = atomicAdd(&curs[q >> 1], 1u << sh);  // LDS atomic
        unsigned pos = off[c] + ((old >> sh) & 0xffffu);
        esrc[pos] = r;  // L2-local slice, plain store
    }
}

// -------- kernel 4: gather bf16 rows -> bf16 agg: dc*(dc*x_c + sum dr*x_r) ------
__global__ __launch_bounds__(256) void k_gather(const unsigned* __restrict__ xh,
                                                const float* __restrict__ dinv,
                                                const unsigned* __restrict__ off,
                                                const unsigned* __restrict__ cnt,
                                                const int* __restrict__ esrc,
                                                unsigned* __restrict__ outh) {
    const int lane = threadIdx.x & 63;
    const int wave = threadIdx.x >> 6;
    const int c = blockIdx.x * 4 + wave;
    if (c >= NN) return;

    const float dc = dinv[c];
    unsigned xc = xh[c * 64 + lane];
    float al = dc * __uint_as_float(xc << 16);
    float ah = dc * __uint_as_float(xc & 0xffff0000u);

    const int base = off[c];
    const int n = cnt[c];
    int i = 0;
    for (; i + 8 <= n; i += 8) {
        int   sv[8];
        float wv[8];
        unsigned pv[8];
        #pragma unroll
        for (int j = 0; j < 8; ++j) sv[j] = esrc[base + i + j];
        #pragma unroll
        for (int j = 0; j < 8; ++j) wv[j] = dinv[sv[j]];
        #pragma unroll
        for (int j = 0; j < 8; ++j) pv[j] = xh[sv[j] * 64 + lane];
        #pragma unroll
        for (int j = 0; j < 8; ++j) {
            al = fmaf(wv[j], __uint_as_float(pv[j] << 16), al);
            ah = fmaf(wv[j], __uint_as_float(pv[j] & 0xffff0000u), ah);
        }
    }
    for (; i + 4 <= n; i += 4) {
        int s0 = esrc[base + i], s1 = esrc[base + i + 1];
        int s2 = esrc[base + i + 2], s3 = esrc[base + i + 3];
        float w0 = dinv[s0], w1 = dinv[s1], w2 = dinv[s2], w3 = dinv[s3];
        unsigned p0 = xh[s0 * 64 + lane], p1 = xh[s1 * 64 + lane];
        unsigned p2 = xh[s2 * 64 + lane], p3 = xh[s3 * 64 + lane];
        al = fmaf(w0, __uint_as_float(p0 << 16), al);
        ah = fmaf(w0, __uint_as_float(p0 & 0xffff0000u), ah);
        al = fmaf(w1, __uint_as_float(p1 << 16), al);
        ah = fmaf(w1, __uint_as_float(p1 & 0xffff0000u), ah);
        al = fmaf(w2, __uint_as_float(p2 << 16), al);
        ah = fmaf(w2, __uint_as_float(p2 & 0xffff0000u), ah);
        al = fmaf(w3, __uint_as_float(p3 << 16), al);
        ah = fmaf(w3, __uint_as_float(p3 & 0xffff0000u), ah);
    }
    for (; i < n; ++i) {
        int s0 = esrc[base + i];
        float w0 = dinv[s0];
        unsigned p0 = xh[s0 * 64 + lane];
        al = fmaf(w0, __uint_as_float(p0 << 16), al);
        ah = fmaf(w0, __uint_as_float(p0 & 0xffff0000u), ah);
    }
    outh[c * 64 + lane] = pk2(al * dc, ah * dc);  // bf16 agg
}

// ---- kernel 5: MFMA GEMM (bf16 A direct) + bias + ReLU -> bf16 rh + BN stats ---
__global__ __launch_bounds__(256, 1) void k_gemm(const unsigned short* __restrict__ aggh,
                                                 unsigned short* __restrict__ rh,
                                                 const unsigned short* __restrict__ Wht,
                                                 const float* __restrict__ b,
                                                 float* __restrict__ sums8) {
    __shared__ float sums_lds[256];
    const int lane = threadIdx.x & 63;
    const int wv = threadIdx.x >> 6;
    const int l15 = lane & 15, l4 = lane >> 4;

    if (threadIdx.x < 256) sums_lds[threadIdx.x] = 0.f;
    __syncthreads();

    short8 bfr[8][4];
    #pragma unroll
    for (int n = 0; n < 8; ++n)
        #pragma unroll
        for (int kk = 0; kk < 4; ++kk)
            bfr[n][kk] = *(const short8*)(Wht + (n * 16 + l15) * D + kk * 32 + l4 * 8);

    float bias8[8];
    #pragma unroll
    for (int n = 0; n < 8; ++n) bias8[n] = b[n * 16 + l15];

    float sl[8], s2l[8];
    #pragma unroll
    for (int n = 0; n < 8; ++n) { sl[n] = 0.f; s2l[n] = 0.f; }

    const int gw = blockIdx.x * 4 + wv;
    #pragma unroll
    for (int t = 0; t < 2; ++t) {
        const int tile = gw * 2 + t;
        if (tile < NN / 16) {
            const int row0 = tile * 16;
            short8 af[4];
            #pragma unroll
            for (int kk = 0; kk < 4; ++kk)
                af[kk] = *(const short8*)(aggh + (row0 + l15) * D + kk * 32 + l4 * 8);
            f32x4 acc[8];
            #pragma unroll
            for (int n = 0; n < 8; ++n) acc[n] = (f32x4){0.f, 0.f, 0.f, 0.f};
            #pragma unroll
            for (int n = 0; n < 8; ++n)
                #pragma unroll
                for (int kk = 0; kk < 4; ++kk)
                    acc[n] = __builtin_amdgcn_mfma_f32_16x16x32_bf16(af[kk], bfr[n][kk],
                                                                     acc[n], 0, 0, 0);
            #pragma unroll
            for (int n = 0; n < 8; ++n)
                #pragma unroll
                for (int j = 0; j < 4; ++j) {
                    int row = row0 + l4 * 4 + j;
                    float v = fmaxf(acc[n][j] + bias8[n], 0.f);
                    rh[row * D + n * 16 + l15] = (unsigned short)bf_rne(v);
                    sl[n] += v;
                    s2l[n] = fmaf(v, v, s2l[n]);
                }
        }
    }

    #pragma unroll
    for (int n = 0; n < 8; ++n) {
        float a = sl[n], q = s2l[n];
        a += __shfl_xor(a, 16); a += __shfl_xor(a, 32);
        q += __shfl_xor(q, 16); q += __shfl_xor(q, 32);
        if (l4 == 0) {
            atomicAdd(&sums_lds[n * 16 + l15], a);
            atomicAdd(&sums_lds[128 + n * 16 + l15], q);
        }
    }
    __syncthreads();
    if (threadIdx.x < 256)
        unsafeAtomicAdd(&sums8[(blockIdx.x & 7) * 256 + threadIdx.x],
                        sums_lds[threadIdx.x]);
}

// ------------- kernel 6: out = rh_bf16 * scale + shift (BN affine) --------------
__global__ __launch_bounds__(256) void k_apply(const unsigned* __restrict__ rh,
                                               float* __restrict__ out,
                                               const float* __restrict__ gamma,
                                               const float* __restrict__ beta,
                                               const float* __restrict__ sums8) {
    const float invN = 1.f / (float)NN;
    const int tid = blockIdx.x * blockDim.x + threadIdx.x;
    const int stride = gridDim.x * blockDim.x;
    const int c4 = (tid & 31) * 4;

    float4 s4 = make_float4(0.f, 0.f, 0.f, 0.f);
    float4 q4 = make_float4(0.f, 0.f, 0.f, 0.f);
    #pragma unroll
    for (int k = 0; k < 8; ++k) {
        float4 a = *(const float4*)&sums8[k * 256 + c4];
        float4 q = *(const float4*)&sums8[k * 256 + 128 + c4];
        s4.x += a.x; s4.y += a.y; s4.z += a.z; s4.w += a.w;
        q4.x += q.x; q4.y += q.y; q4.z += q.z; q4.w += q.w;
    }
    float4 g4 = *(const float4*)&gamma[c4];
    float4 be = *(const float4*)&beta[c4];

    float mx = s4.x * invN, my = s4.y * invN, mz = s4.z * invN, mw = s4.w * invN;
    float scx = g4.x * rsqrtf(fmaxf(q4.x * invN - mx * mx, 0.f) + BN_EPS);
    float scy = g4.y * rsqrtf(fmaxf(q4.y * invN - my * my, 0.f) + BN_EPS);
    float scz = g4.z * rsqrtf(fmaxf(q4.z * invN - mz * mz, 0.f) + BN_EPS);
    float scw = g4.w * rsqrtf(fmaxf(q4.w * invN - mw * mw, 0.f) + BN_EPS);
    float shx = be.x - mx * scx, shy = be.y - my * scy;
    float shz = be.z - mz * scz, shw = be.w - mw * scw;

    for (int idx = tid; idx < NN * (D / 4); idx += stride) {
        const int row = idx >> 5;
        uint2 p = *(const uint2*)&rh[row * 64 + (tid & 31) * 2];
        float4 a;
        a.x = __uint_as_float(p.x << 16);
        a.y = __uint_as_float(p.x & 0xffff0000u);
        a.z = __uint_as_float(p.y << 16);
        a.w = __uint_as_float(p.y & 0xffff0000u);
        a.x = a.x * scx + shx;
        a.y = a.y * scy + shy;
        a.z = a.z * scz + shz;
        a.w = a.w * scw + shw;
        ((float4*)out)[idx] = a;
    }
}

extern "C" void kernel_launch(void* const* d_in, const int* in_sizes, int n_in,
                              void* d_out, int out_size, void* d_ws, size_t ws_size,
                              hipStream_t stream) {
    const float* x     = (const float*)d_in[0];
    const int*   ei    = (const int*)d_in[1];
    const float* W     = (const float*)d_in[2];
    const float* b     = (const float*)d_in[3];
    const float* gamma = (const float*)d_in[4];
    const float* beta  = (const float*)d_in[5];
    float*       out   = (float*)d_out;

    char* ws = (char*)d_ws;
    float*          dinv  = (float*)ws;
    unsigned*       cnt   = (unsigned*)(ws + 400000);
    unsigned*       off   = (unsigned*)(ws + 800000);
    unsigned*       part  = (unsigned*)(ws + 1200000);
    float*          sums8 = (float*)(ws + 1202048);
    int*            esrc  = (int*)(ws + 1210368);
    unsigned*       hist  = (unsigned*)(ws + 7610368);   // 12.8 MB
    unsigned*       xh    = (unsigned*)(ws + 20410368);  // 25.6 MB; rh after gather
    unsigned short* Wht   = (unsigned short*)(ws + 46010368);

    k_hist<<<256 + NCVT, 1024, 0, stream>>>(ei, hist, x, xh);
    k_reduce<<<(4 * HW8 + D * D + 2048 + 255) / 256, 256, 0, stream>>>(hist, cnt, dinv, W, Wht, part, sums8);
    k_scan3<<<NPART, 256, 0, stream>>>(cnt, part, off);
    k_scatter<<<NCH * 4, 1024, 0, stream>>>(ei, off, hist, esrc);
    k_gather<<<25000, 256, 0, stream>>>(xh, dinv, off, cnt, esrc, (unsigned*)out);
    k_gemm<<<782, 256, 0, stream>>>((const unsigned short*)out, (unsigned short*)xh, Wht, b, sums8);
    k_apply<<<2048, 256, 0, stream>>>(xh, out, gamma, beta, sums8);
}